// Round 4
// baseline (9158.546 us; speedup 1.0000x reference)
//
#include <hip/hip_runtime.h>
#include <hip/hip_bf16.h>
#include <math.h>

typedef __hip_bfloat16 bf16;

static constexpr int B_C   = 32;
static constexpr int N_C   = 32;
static constexpr int E_C   = 64;
static constexpr int HW_C  = 1600;
static constexpr int D_C   = 256;
static constexpr int NH_C  = 8;
static constexpr int DH_C  = 32;
static constexpr int L_C   = 6;
static constexpr int TN_C  = 1024;   // B*N
static constexpr int TE_C  = 2048;   // B*E
static constexpr int TT_C  = 3072;   // TN+TE
static constexpr int CB_C  = 4;      // batches per attention chunk

__device__ __forceinline__ float bf2f(bf16 v) { return __bfloat162float(v); }
__device__ __forceinline__ int clampi(int v, int lo, int hi) {
  return v < lo ? lo : (v > hi ? hi : v);
}
__device__ __forceinline__ float clampf(float v, float lo, float hi) {
  return fminf(fmaxf(v, lo), hi);
}

__device__ __forceinline__ void unpack_bf2(unsigned v, float& a, float& b) {
  union { unsigned u; float f; } ua, ub;
  ua.u = v << 16;
  ub.u = v & 0xffff0000u;
  a = ua.f; b = ub.f;
}

// load 32 contiguous bf16 (64B, 16B-aligned) into 32 floats
__device__ __forceinline__ void load_bf16x32(const bf16* p, float* out) {
  const uint4* p4 = reinterpret_cast<const uint4*>(p);
#pragma unroll
  for (int w = 0; w < 4; w++) {
    uint4 u = p4[w];
    unpack_bf2(u.x, out[w * 8 + 0], out[w * 8 + 1]);
    unpack_bf2(u.y, out[w * 8 + 2], out[w * 8 + 3]);
    unpack_bf2(u.z, out[w * 8 + 4], out[w * 8 + 5]);
    unpack_bf2(u.w, out[w * 8 + 6], out[w * 8 + 7]);
  }
}

// ---------------- generic tiled GEMM: C(M,N) = A(M,K) @ B +(epilogue) ------
// All inputs float32. BT=true: B is (N,K) row-major -> A @ B^T; else (K,N).
// EPI: 0 none, 1 +bias, 2 +bias then exact GELU, 3 accumulate into C
template <bool BT, int EPI, typename TC>
__global__ __launch_bounds__(256) void gemm_kernel(
    const float* __restrict__ A, int lda, const float* __restrict__ Bw, int ldb,
    const float* __restrict__ bias, TC* __restrict__ C, int ldc,
    int M, int N, int K)
{
  __shared__ float As[16][64];
  __shared__ float Bs[16][64];
  const int tid = threadIdx.x;
  const int bm = blockIdx.x, bn = blockIdx.y;
  const int tx = tid & 15, ty = tid >> 4;
  const int row0 = bm * 64, col0 = bn * 64;
  float acc[4][4] = {};

  for (int k0 = 0; k0 < K; k0 += 16) {
#pragma unroll
    for (int c = 0; c < 4; c++) {
      int idx = tid + 256 * c;
      int m = idx >> 4, kk = idx & 15;
      As[kk][m] = A[(size_t)(row0 + m) * lda + k0 + kk];
    }
    if (BT) {
#pragma unroll
      for (int c = 0; c < 4; c++) {
        int idx = tid + 256 * c;
        int n = idx >> 4, kk = idx & 15;
        Bs[kk][n] = Bw[(size_t)(col0 + n) * ldb + k0 + kk];
      }
    } else {
#pragma unroll
      for (int c = 0; c < 4; c++) {
        int idx = tid + 256 * c;
        int n = idx & 63, kk = idx >> 6;
        Bs[kk][n] = Bw[(size_t)(k0 + kk) * ldb + col0 + n];
      }
    }
    __syncthreads();
#pragma unroll
    for (int kk = 0; kk < 16; kk++) {
      float a[4], b[4];
#pragma unroll
      for (int i = 0; i < 4; i++) a[i] = As[kk][ty * 4 + i];
#pragma unroll
      for (int j = 0; j < 4; j++) b[j] = Bs[kk][tx * 4 + j];
#pragma unroll
      for (int i = 0; i < 4; i++)
#pragma unroll
        for (int j = 0; j < 4; j++)
          acc[i][j] = fmaf(a[i], b[j], acc[i][j]);
    }
    __syncthreads();
  }

#pragma unroll
  for (int i = 0; i < 4; i++) {
    int r = row0 + ty * 4 + i;
#pragma unroll
    for (int j = 0; j < 4; j++) {
      int cc = col0 + tx * 4 + j;
      float v = acc[i][j];
      TC* cp = C + (size_t)r * ldc + cc;
      if (EPI == 1 || EPI == 2) v += bias[cc];
      if (EPI == 2) v = 0.5f * v * (1.0f + erff(v * 0.70710678118654752f));
      if (EPI == 3) v += (float)(*cp);
      *cp = (TC)v;
    }
  }
}

template <bool BT, int EPI, typename TC>
static void launch_gemm(const float* A, int lda, const float* Bw, int ldb,
                        const float* bias, void* C, int ldc,
                        int M, int N, int K, hipStream_t s) {
  dim3 g(M / 64, N / 64);
  gemm_kernel<BT, EPI, TC><<<g, 256, 0, s>>>(
      A, lda, Bw, ldb, bias, (TC*)C, ldc, M, N, K);
}

// ---------------- precompute kernels ----------------

__global__ __launch_bounds__(256) void embq_kernel(const float* __restrict__ boxes,
                                                   const int* __restrict__ el,
                                                   float* __restrict__ emb) {
  int t = blockIdx.x;
  int d = threadIdx.x;
  int c = d >> 6, inner = d & 63;
  float v;
  if (t < TN_C) {
    v = boxes[t * 4 + c];
  } else {
    int e = t - TN_C;
    int b = e >> 6;
    int sg = clampi(el[e], 0, N_C - 1) + b * N_C;
    int dg = clampi(el[TE_C + e], 0, N_C - 1) + b * N_C;
    v = boxes[sg * 4 + c] - boxes[dg * 4 + c];
  }
  v = clampf(v, -100.f, 100.f);
  int i = inner & 31;
  float freq = expf(-9.210340371976184f * (float)i / 32.0f);
  float ang = v * freq;
  emb[(size_t)t * D_C + d] = (inner < 32) ? sinf(ang) : cosf(ang);
}

__global__ __launch_bounds__(256) void initq_kernel(const float* __restrict__ nodes0,
                                                    const float* __restrict__ edges0,
                                                    float* __restrict__ q) {
  int idx = blockIdx.x * 256 + threadIdx.x;
  int t = idx >> 8;
  q[idx] = (t < TN_C) ? nodes0[idx] : edges0[idx - TN_C * D_C];
}

// ---------------- LayerNorm (optionally writes xe = x + emb) ---------------

__global__ __launch_bounds__(256) void ln_kernel(const float* __restrict__ qin,
                                                 const float* __restrict__ g,
                                                 const float* __restrict__ bb,
                                                 float* __restrict__ xout,
                                                 const float* __restrict__ emb,
                                                 float* __restrict__ xeout) {
  __shared__ float red[4];
  int r = blockIdx.x, tid = threadIdx.x;
  size_t base = (size_t)r * D_C;
  float v = qin[base + tid];
  float s = v;
#pragma unroll
  for (int o = 1; o < 64; o <<= 1) s += __shfl_xor(s, o);
  if ((tid & 63) == 0) red[tid >> 6] = s;
  __syncthreads();
  float mean = (red[0] + red[1] + red[2] + red[3]) * (1.0f / 256.0f);
  __syncthreads();
  float d = v - mean;
  float s2 = d * d;
#pragma unroll
  for (int o = 1; o < 64; o <<= 1) s2 += __shfl_xor(s2, o);
  if ((tid & 63) == 0) red[tid >> 6] = s2;
  __syncthreads();
  float var = (red[0] + red[1] + red[2] + red[3]) * (1.0f / 256.0f);
  float xo = d * rsqrtf(var + 1e-5f) * g[tid] + bb[tid];
  xout[base + tid] = xo;
  if (xeout) xeout[base + tid] = xo + emb[base + tid];
}

// ---------------- attention: one wave per (token-in-chunk, head) -----------
// KV: (CB*HW, 512) bf16 for batches [c0, c0+CB). cols 0..255 K, 256..511 V.
// Bias recomputed on the fly from boxes (node: 1 gaussian; edge: max of 3).

__global__ __launch_bounds__(256) void attn_kernel(const float* __restrict__ Qp,
                                                   const bf16* __restrict__ KV,
                                                   const float* __restrict__ boxes,
                                                   const int* __restrict__ el,
                                                   int c0,
                                                   float* __restrict__ O) {
  int wid = threadIdx.x >> 6;
  int lane = threadIdx.x & 63;
  int gw = blockIdx.x * 4 + wid;           // 0 .. CB*96*8-1
  int tic = gw >> 3, h = gw & 7;           // tic 0..383
  int t, bl, nG;
  float pcx[3], pcy[3], pdx[3], pdy[3];
  if (tic < CB_C * N_C) {                  // node token
    bl = tic >> 5;
    t = (c0 + bl) * N_C + (tic & 31);
    float cx = clampf(boxes[t * 4 + 0], -10.f, 10.f);
    float cy = clampf(boxes[t * 4 + 1], -10.f, 10.f);
    float w  = clampf(boxes[t * 4 + 2], -10.f, 10.f);
    float hh = clampf(boxes[t * 4 + 3], -10.f, 10.f);
    pcx[0] = cx; pcy[0] = cy;
    pdx[0] = w * w * 0.5f + 1e-6f; pdy[0] = hh * hh * 0.5f + 1e-6f;
    nG = 1;
  } else {                                 // edge token
    int ei = tic - CB_C * N_C;
    bl = ei >> 6;
    int e = (c0 + bl) * E_C + (ei & 63);
    t = TN_C + e;
    int sg = clampi(el[e], 0, N_C - 1) + (c0 + bl) * N_C;
    int dg = clampi(el[TE_C + e], 0, N_C - 1) + (c0 + bl) * N_C;
    float c1x = clampf(boxes[sg * 4 + 0], -10.f, 10.f);
    float c1y = clampf(boxes[sg * 4 + 1], -10.f, 10.f);
    float w1  = clampf(boxes[sg * 4 + 2], -10.f, 10.f);
    float h1  = clampf(boxes[sg * 4 + 3], -10.f, 10.f);
    float c2x = clampf(boxes[dg * 4 + 0], -10.f, 10.f);
    float c2y = clampf(boxes[dg * 4 + 1], -10.f, 10.f);
    float w2  = clampf(boxes[dg * 4 + 2], -10.f, 10.f);
    float h2  = clampf(boxes[dg * 4 + 3], -10.f, 10.f);
    pcx[0] = c1x; pcy[0] = c1y;
    pdx[0] = w1 * w1 * 0.5f + 1e-6f; pdy[0] = h1 * h1 * 0.5f + 1e-6f;
    pcx[1] = c2x; pcy[1] = c2y;
    pdx[1] = w2 * w2 * 0.5f + 1e-6f; pdy[1] = h2 * h2 * 0.5f + 1e-6f;
    float ux1 = fminf(c1x - w1 * 0.5f, c2x - w2 * 0.5f);
    float uy1 = fminf(c1y - h1 * 0.5f, c2y - h2 * 0.5f);
    float ux2 = fmaxf(c1x + w1 * 0.5f, c2x + w2 * 0.5f);
    float uy2 = fmaxf(c1y + h1 * 0.5f, c2y + h2 * 0.5f);
    float uw = ux2 - ux1, uh = uy2 - uy1;
    pcx[2] = 0.5f * (ux1 + ux2); pcy[2] = 0.5f * (uy1 + uy2);
    pdx[2] = uw * uw * 0.5f + 1e-6f; pdy[2] = uh * uh * 0.5f + 1e-6f;
    nG = 3;
  }

  float qv[32];
  const float* qp = Qp + (size_t)t * D_C + h * DH_C;
#pragma unroll
  for (int d = 0; d < 32; d++) qv[d] = qp[d];

  const float scale = 0.17677669529663687f;  // 1/sqrt(32)
  const bf16* kvb = KV + (size_t)bl * HW_C * 512 + h * DH_C;

  float sarr[25];
  float m = -1e30f;
#pragma unroll
  for (int i = 0; i < 25; i++) {
    int kk = lane + i * 64;
    float kf[32];
    load_bf16x32(kvb + (size_t)kk * 512, kf);
    float s = 0.f;
#pragma unroll
    for (int d = 0; d < 32; d++) s = fmaf(kf[d], qv[d], s);
    // bias on the fly
    int yy = kk / 40, xx = kk - yy * 40;
    float gx = ((float)xx + 0.5f) * 0.025f;
    float gy = ((float)yy + 0.5f) * 0.025f;
    float bias = 0.f;
    for (int g = 0; g < nG; g++) {
      float dxv = gx - pcx[g], dyv = gy - pcy[g];
      float e = expf(-dxv * dxv / pdx[g]) * expf(-dyv * dyv / pdy[g]);
      bias = fmaxf(bias, e);
    }
    s = clampf(s * scale + bias, -1e30f, 1e30f);
    sarr[i] = s;
    m = fmaxf(m, s);
  }
#pragma unroll
  for (int o = 1; o < 64; o <<= 1) m = fmaxf(m, __shfl_xor(m, o));

  float l = 0.f;
  float acc[32] = {};
#pragma unroll
  for (int i = 0; i < 25; i++) {
    int kk = lane + i * 64;
    float vf[32];
    load_bf16x32(kvb + (size_t)kk * 512 + 256, vf);
    float e = expf(fminf(sarr[i] - m, 0.f));
    l += e;
#pragma unroll
    for (int d = 0; d < 32; d++) acc[d] = fmaf(e, vf[d], acc[d]);
  }
#pragma unroll
  for (int o = 1; o < 64; o <<= 1) {
    l += __shfl_xor(l, o);
#pragma unroll
    for (int d = 0; d < 32; d++) acc[d] += __shfl_xor(acc[d], o);
  }
  if (lane == 0) {
    float inv = 1.0f / fmaxf(l, 1e-30f);
    float* op = O + (size_t)t * D_C + h * DH_C;
#pragma unroll
    for (int d = 0; d < 32; d++) op[d] = acc[d] * inv;
  }
}

// ---------------- GAT kernels ----------------

__global__ __launch_bounds__(256) void gat_logits_kernel(const float* __restrict__ hee,
                                                         const int* __restrict__ el,
                                                         const float* __restrict__ as,
                                                         const float* __restrict__ ad,
                                                         const float* __restrict__ ae,
                                                         float* __restrict__ logits) {
  int idx = blockIdx.x * 256 + threadIdx.x;  // Te*NH
  int e = idx >> 3, h = idx & 7;
  int b = e >> 6;
  int sg = clampi(el[e], 0, N_C - 1) + b * N_C;
  int dg = clampi(el[TE_C + e], 0, N_C - 1) + b * N_C;
  const float* hs = hee + (size_t)sg * D_C + h * DH_C;
  const float* hd = hee + (size_t)dg * D_C + h * DH_C;
  const float* ep = hee + (size_t)(TN_C + e) * D_C + h * DH_C;
  float s = 0.f;
#pragma unroll
  for (int d = 0; d < 32; d++) {
    s += hs[d] * as[h * 32 + d] + hd[d] * ad[h * 32 + d] + ep[d] * ae[h * 32 + d];
  }
  s = clampf(s, -1e30f, 1e30f);
  logits[idx] = (s > 0.f) ? s : 0.2f * s;
}

__global__ __launch_bounds__(256) void gat_mden_kernel(const float* __restrict__ logits,
                                                       const int* __restrict__ el,
                                                       float* __restrict__ mb,
                                                       float* __restrict__ db) {
  int idx = blockIdx.x * 256 + threadIdx.x;  // Tn*NH
  int n = idx >> 3, h = idx & 7;
  int b = n >> 5;
  int e0 = b * E_C;
  float m = -1e30f;
  for (int k = 0; k < 64; k++) {
    int dg = clampi(el[TE_C + e0 + k], 0, N_C - 1) + b * N_C;
    if (dg == n) m = fmaxf(m, logits[(e0 + k) * 8 + h]);
  }
  float den = 0.f;
  for (int k = 0; k < 64; k++) {
    int dg = clampi(el[TE_C + e0 + k], 0, N_C - 1) + b * N_C;
    if (dg == n) den += expf(fminf(logits[(e0 + k) * 8 + h] - m, 0.f));
  }
  mb[idx] = m;
  db[idx] = den;
}

__global__ __launch_bounds__(256) void gat_alpha_kernel(const float* __restrict__ logits,
                                                        const int* __restrict__ el,
                                                        const float* __restrict__ mb,
                                                        const float* __restrict__ db,
                                                        float* __restrict__ al) {
  int idx = blockIdx.x * 256 + threadIdx.x;  // Te*NH
  int e = idx >> 3, h = idx & 7;
  int b = e >> 6;
  int dg = clampi(el[TE_C + e], 0, N_C - 1) + b * N_C;
  float ex = expf(fminf(logits[idx] - mb[dg * 8 + h], 0.f));
  al[idx] = ex / (db[dg * 8 + h] + 1e-9f);
}

__global__ __launch_bounds__(256) void gat_nout_kernel(const float* __restrict__ hee,
                                                       const int* __restrict__ el,
                                                       const float* __restrict__ al,
                                                       float* __restrict__ noutp) {
  int n = blockIdx.x, d = threadIdx.x;
  int h = d >> 5;
  int b = n >> 5;
  int e0 = b * E_C;
  float acc = 0.f;
  for (int k = 0; k < 64; k++) {
    int e = e0 + k;
    int dg = clampi(el[TE_C + e], 0, N_C - 1) + b * N_C;
    if (dg == n) {
      int sg = clampi(el[e], 0, N_C - 1) + b * N_C;
      acc += al[e * 8 + h] * (hee[(size_t)sg * D_C + d] + hee[(size_t)(TN_C + e) * D_C + d]);
    }
  }
  noutp[(size_t)n * D_C + d] = acc;
}

// ---------------- elementwise residual kernels ----------------

__global__ __launch_bounds__(256) void axpy_kernel(float* __restrict__ q,
                                                   const float* __restrict__ delta,
                                                   const float* __restrict__ ls) {
  int idx = blockIdx.x * 256 + threadIdx.x;
  q[idx] += ls[idx & 255] * delta[idx];
}

__global__ __launch_bounds__(256) void axpy_store_kernel(float* __restrict__ q,
                                                         const float* __restrict__ delta,
                                                         const float* __restrict__ ls,
                                                         float* __restrict__ out) {
  int idx = blockIdx.x * 256 + threadIdx.x;
  float v = q[idx] + ls[idx & 255] * delta[idx];
  q[idx] = v;
  out[idx] = v;
}

__global__ __launch_bounds__(256) void base_add_kernel(float* __restrict__ q,
                                                       const float* __restrict__ xbase,
                                                       const float* __restrict__ delta,
                                                       const float* __restrict__ ls) {
  int idx = blockIdx.x * 256 + threadIdx.x;
  q[idx] = xbase[idx] + ls[idx & 255] * delta[idx];
}

// Final pass: kill NaN/inf so corruption yields a finite diagnostic absmax.
__global__ __launch_bounds__(256) void sanitize_kernel(float* __restrict__ out) {
  int idx = blockIdx.x * 256 + threadIdx.x;
  float v = out[idx];
  if (!(fabsf(v) <= 1e4f)) out[idx] = 0.f;
}

// ---------------- host ----------------

extern "C" void kernel_launch(void* const* d_in, const int* in_sizes, int n_in,
                              void* d_out, int out_size, void* d_ws, size_t ws_size,
                              hipStream_t stream) {
  const float* features   = (const float*)d_in[0];
  const float* boxes      = (const float*)d_in[1];
  const int*   edge_local = (const int*)d_in[2];
  const float* nodes0     = (const float*)d_in[3];
  const float* edges0     = (const float*)d_in[4];
  const float* ln1_g      = (const float*)d_in[5];
  const float* ln1_b      = (const float*)d_in[6];
  const float* attn_in_w  = (const float*)d_in[7];
  const float* attn_in_b  = (const float*)d_in[8];
  const float* attn_out_w = (const float*)d_in[9];
  const float* attn_out_b = (const float*)d_in[10];
  const float* ls1        = (const float*)d_in[11];
  const float* ln2_g      = (const float*)d_in[12];
  const float* ln2_b      = (const float*)d_in[13];
  const float* gat_wn     = (const float*)d_in[14];
  const float* gat_we     = (const float*)d_in[15];
  const float* gat_a_src  = (const float*)d_in[16];
  const float* gat_a_dst  = (const float*)d_in[17];
  const float* gat_a_edge = (const float*)d_in[18];
  const float* gat_wo     = (const float*)d_in[19];
  const float* gat_bo     = (const float*)d_in[20];
  const float* gat_woe    = (const float*)d_in[21];
  const float* gat_boe    = (const float*)d_in[22];
  const float* ls2        = (const float*)d_in[23];
  const float* ln3_g      = (const float*)d_in[24];
  const float* ln3_b      = (const float*)d_in[25];
  const float* ffn_w1     = (const float*)d_in[26];
  const float* ffn_b1     = (const float*)d_in[27];
  const float* ffn_w2     = (const float*)d_in[28];
  const float* ffn_b2     = (const float*)d_in[29];
  const float* ls3        = (const float*)d_in[30];
  float* out = (float*)d_out;

  // workspace layout — total ~26 MB
  size_t off = 0;
  auto alloc = [&](size_t bytes) -> void* {
    void* p = (char*)d_ws + off;
    off += (bytes + 255) & ~(size_t)255;
    return p;
  };
  const size_t TD = (size_t)TT_C * D_C;
  float* emb   = (float*)alloc(TD * 4);                             // 3.15 MB
  float* q     = (float*)alloc(TD * 4);                             // 3.15 MB
  float* t0    = (float*)alloc(TD * 4);                             // 3.15 MB
  float* t1    = (float*)alloc(TD * 4);                             // 3.15 MB
  float* ybig  = (float*)alloc((size_t)TT_C * 512 * 4);             // 6.29 MB
  bf16*  KV    = (bf16*)alloc((size_t)CB_C * HW_C * 512 * 2);       // 6.55 MB
  float* logits= (float*)alloc((size_t)TE_C * 8 * 4);
  float* mb    = (float*)alloc((size_t)TN_C * 8 * 4);
  float* db    = (float*)alloc((size_t)TN_C * 8 * 4);
  float* al    = (float*)alloc((size_t)TE_C * 8 * 4);
  float* hee   = ybig;                                              // aliased
  float* noutp = ybig + (size_t)TT_C * 256;                         // after hee
  (void)ws_size; (void)in_sizes; (void)n_in; (void)out_size;

  // precompute
  embq_kernel<<<TT_C, 256, 0, stream>>>(boxes, edge_local, emb);
  initq_kernel<<<TT_C, 256, 0, stream>>>(nodes0, edges0, q);

  for (int l = 0; l < L_C; l++) {
    const float* Wq  = attn_in_w + (size_t)l * 768 * 256;
    const float* WKV = Wq + (size_t)256 * 256;
    const float* bq  = attn_in_b + (size_t)l * 768;
    const float* bKV = bq + 256;

    // LN1: q -> t0
    ln_kernel<<<TT_C, 256, 0, stream>>>(q, ln1_g + l * 256, ln1_b + l * 256,
                                        t0, nullptr, nullptr);
    // Q projection: t0 @ Wq^T + bq -> t1
    launch_gemm<true, 1, float>(t0, 256, Wq, 256, bq, t1, 256,
                                TT_C, 256, 256, stream);
    // chunked K/V projection + attention (attn writes o into t0)
    for (int c = 0; c < B_C / CB_C; c++) {
      launch_gemm<true, 1, bf16>(features + (size_t)c * CB_C * HW_C * 256, 256,
                                 WKV, 256, bKV, KV, 512,
                                 CB_C * HW_C, 512, 256, stream);
      attn_kernel<<<(CB_C * (N_C + E_C) * NH_C) / 4, 256, 0, stream>>>(
          t1, KV, boxes, edge_local, c * CB_C, t0);
    }
    // output projection: t0 @ Wo^T + bo -> t1
    launch_gemm<true, 1, float>(t0, 256, attn_out_w + (size_t)l * 65536, 256,
                                attn_out_b + l * 256, t1, 256,
                                TT_C, 256, 256, stream);
    // q += ls1 * t1
    axpy_kernel<<<TT_C, 256, 0, stream>>>(q, t1, ls1 + l * 256);
    // LN2: q -> x2=t0, xe=t1
    ln_kernel<<<TT_C, 256, 0, stream>>>(q, ln2_g + l * 256, ln2_b + l * 256,
                                        t0, emb, t1);
    // GAT projections -> hee (in ybig)
    launch_gemm<false, 0, float>(t1, 256, gat_wn + (size_t)l * 65536, 256,
                                 nullptr, hee, 256, TN_C, 256, 256, stream);
    launch_gemm<false, 0, float>(t1 + (size_t)TN_C * 256, 256,
                                 gat_we + (size_t)l * 65536, 256, nullptr,
                                 hee + (size_t)TN_C * 256, 256,
                                 TE_C, 256, 256, stream);
    // GAT attention
    gat_logits_kernel<<<(TE_C * 8) / 256, 256, 0, stream>>>(
        hee, edge_local, gat_a_src + l * 256, gat_a_dst + l * 256,
        gat_a_edge + l * 256, logits);
    gat_mden_kernel<<<(TN_C * 8) / 256, 256, 0, stream>>>(logits, edge_local, mb, db);
    gat_alpha_kernel<<<(TE_C * 8) / 256, 256, 0, stream>>>(logits, edge_local, mb, db, al);
    gat_nout_kernel<<<TN_C, 256, 0, stream>>>(hee, edge_local, al, noutp);
    // GAT output projections -> t1 (xe dead)
    launch_gemm<false, 1, float>(noutp, 256, gat_wo + (size_t)l * 65536, 256,
                                 gat_bo + l * 256, t1, 256,
                                 TN_C, 256, 256, stream);
    launch_gemm<false, 1, float>(hee + (size_t)TN_C * 256, 256,
                                 gat_woe + (size_t)l * 65536, 256,
                                 gat_boe + l * 256, t1 + (size_t)TN_C * 256, 256,
                                 TE_C, 256, 256, stream);
    // q = x2(t0) + ls2 * t1
    base_add_kernel<<<TT_C, 256, 0, stream>>>(q, t0, t1, ls2 + l * 256);
    // LN3: q -> t0
    ln_kernel<<<TT_C, 256, 0, stream>>>(q, ln3_g + l * 256, ln3_b + l * 256,
                                        t0, nullptr, nullptr);
    // FFN in two 512-wide halves through ybig
    const float* W1 = ffn_w1 + (size_t)l * 262144;
    const float* W2 = ffn_w2 + (size_t)l * 262144;
    // half A: y = gelu(t0 @ W1[:,0:512] + b1[0:512]); t1 = y @ W2[0:512,:] + b2
    launch_gemm<false, 2, float>(t0, 256, W1, 1024, ffn_b1 + l * 1024,
                                 ybig, 512, TT_C, 512, 256, stream);
    launch_gemm<false, 1, float>(ybig, 512, W2, 256, ffn_b2 + l * 256,
                                 t1, 256, TT_C, 256, 512, stream);
    // half B: y = gelu(t0 @ W1[:,512:1024] + b1[512:]); t1 += y @ W2[512:,:]
    launch_gemm<false, 2, float>(t0, 256, W1 + 512, 1024,
                                 ffn_b1 + l * 1024 + 512,
                                 ybig, 512, TT_C, 512, 256, stream);
    launch_gemm<false, 3, float>(ybig, 512, W2 + (size_t)512 * 256, 256,
                                 nullptr, t1, 256, TT_C, 256, 512, stream);
    // q += ls3 * t1 ; store layer output
    axpy_store_kernel<<<TT_C, 256, 0, stream>>>(q, t1, ls3 + l * 256,
                                                out + (size_t)l * TD);
  }
  // diagnostic / defensive: remove NaN/inf from output
  sanitize_kernel<<<(L_C * (int)TD) / 256, 256, 0, stream>>>(out);
}

// Round 5
// 6529.623 us; speedup vs baseline: 1.4026x; 1.4026x over previous
//
#include <hip/hip_runtime.h>
#include <hip/hip_bf16.h>
#include <math.h>

typedef __hip_bfloat16 bf16;
typedef unsigned short ushort_t;
typedef __attribute__((ext_vector_type(8))) short bf16x8;
typedef __attribute__((ext_vector_type(4))) float f32x4;

static constexpr int B_C   = 32;
static constexpr int N_C   = 32;
static constexpr int E_C   = 64;
static constexpr int HW_C  = 1600;
static constexpr int D_C   = 256;
static constexpr int NH_C  = 8;
static constexpr int DH_C  = 32;
static constexpr int L_C   = 6;
static constexpr int TN_C  = 1024;   // B*N
static constexpr int TE_C  = 2048;   // B*E
static constexpr int TT_C  = 3072;   // TN+TE

__device__ __forceinline__ float bf2f(bf16 v) { return __bfloat162float(v); }
__device__ __forceinline__ int clampi(int v, int lo, int hi) {
  return v < lo ? lo : (v > hi ? hi : v);
}
__device__ __forceinline__ float clampf(float v, float lo, float hi) {
  return fminf(fmaxf(v, lo), hi);
}
__device__ __forceinline__ ushort_t f2b(float x) {
  bf16 h = __float2bfloat16(x);
  return *reinterpret_cast<ushort_t*>(&h);
}

__device__ __forceinline__ void unpack_bf2(unsigned v, float& a, float& b) {
  union { unsigned u; float f; } ua, ub;
  ua.u = v << 16;
  ub.u = v & 0xffff0000u;
  a = ua.f; b = ub.f;
}

// load 32 contiguous bf16 (64B, 16B-aligned) into 32 floats
__device__ __forceinline__ void load_bf16x32(const bf16* p, float* out) {
  const uint4* p4 = reinterpret_cast<const uint4*>(p);
#pragma unroll
  for (int w = 0; w < 4; w++) {
    uint4 u = p4[w];
    unpack_bf2(u.x, out[w * 8 + 0], out[w * 8 + 1]);
    unpack_bf2(u.y, out[w * 8 + 2], out[w * 8 + 3]);
    unpack_bf2(u.z, out[w * 8 + 4], out[w * 8 + 5]);
    unpack_bf2(u.w, out[w * 8 + 6], out[w * 8 + 7]);
  }
}

// ============ MFMA bf16 GEMM: C(M,N) = A(M,K)@B (+epilogue) ===============
// A is f32 (M,lda) row-major, converted to bf16 during LDS staging.
// BT=true : B f32 (N,K) row-major -> A @ B^T ; BT=false: B f32 (K,N) -> A @ B
// EPI: 0 none, 1 +bias, 2 +bias then exact GELU, 3 accumulate into C
// 64x64 tile, BK=32, 4 waves in 2x2, each wave 32x32 via 2x2 mfma 16x16x32.
static constexpr int SA = 40;  // LDS row stride in shorts (pad vs 32)

__device__ __forceinline__ void stage8(const float* __restrict__ src,
                                       ushort_t* __restrict__ dst) {
  float4 f0 = *(const float4*)src;
  float4 f1 = *(const float4*)(src + 4);
  ushort_t t[8] = { f2b(f0.x), f2b(f0.y), f2b(f0.z), f2b(f0.w),
                    f2b(f1.x), f2b(f1.y), f2b(f1.z), f2b(f1.w) };
  *(uint4*)dst = *(const uint4*)t;
}

template <bool BT, int EPI, typename TC>
__global__ __launch_bounds__(256) void mgemm_kernel(
    const float* __restrict__ A, int lda, const float* __restrict__ Bw, int ldb,
    const float* __restrict__ bias, TC* __restrict__ C, int ldc,
    int M, int N, int K)
{
  __shared__ ushort_t As[64 * SA];
  __shared__ ushort_t Bs[64 * SA];
  const int tid = threadIdx.x;
  const int row0 = blockIdx.x * 64, col0 = blockIdx.y * 64;
  const int wave = tid >> 6, lane = tid & 63;
  const int wm = (wave >> 1) * 32, wn = (wave & 1) * 32;
  const int lm = lane & 15, quad = lane >> 4;

  f32x4 acc[2][2] = {};

  const int am = tid >> 2, akk = (tid & 3) * 8;       // A staging coords
  const int bn = tid & 63, bkb = (tid >> 6) * 8;      // B staging (BT=false)

  for (int k0 = 0; k0 < K; k0 += 32) {
    stage8(A + (size_t)(row0 + am) * lda + k0 + akk, &As[am * SA + akk]);
    if (BT) {
      stage8(Bw + (size_t)(col0 + am) * ldb + k0 + akk, &Bs[am * SA + akk]);
    } else {
      ushort_t t[8];
#pragma unroll
      for (int j = 0; j < 8; j++)
        t[j] = f2b(Bw[(size_t)(k0 + bkb + j) * ldb + col0 + bn]);
      *(uint4*)(&Bs[bn * SA + bkb]) = *(const uint4*)t;
    }
    __syncthreads();
    bf16x8 a0 = *(const bf16x8*)(&As[(wm + lm) * SA + quad * 8]);
    bf16x8 a1 = *(const bf16x8*)(&As[(wm + 16 + lm) * SA + quad * 8]);
    bf16x8 b0 = *(const bf16x8*)(&Bs[(wn + lm) * SA + quad * 8]);
    bf16x8 b1 = *(const bf16x8*)(&Bs[(wn + 16 + lm) * SA + quad * 8]);
    acc[0][0] = __builtin_amdgcn_mfma_f32_16x16x32_bf16(a0, b0, acc[0][0], 0, 0, 0);
    acc[0][1] = __builtin_amdgcn_mfma_f32_16x16x32_bf16(a0, b1, acc[0][1], 0, 0, 0);
    acc[1][0] = __builtin_amdgcn_mfma_f32_16x16x32_bf16(a1, b0, acc[1][0], 0, 0, 0);
    acc[1][1] = __builtin_amdgcn_mfma_f32_16x16x32_bf16(a1, b1, acc[1][1], 0, 0, 0);
    __syncthreads();
  }

#pragma unroll
  for (int ti = 0; ti < 2; ti++) {
#pragma unroll
    for (int tj = 0; tj < 2; tj++) {
      int gc = col0 + wn + tj * 16 + lm;
      float bsv = (EPI == 1 || EPI == 2) ? bias[gc] : 0.f;
#pragma unroll
      for (int r = 0; r < 4; r++) {
        int gr = row0 + wm + ti * 16 + quad * 4 + r;
        float v = acc[ti][tj][r];
        TC* cp = C + (size_t)gr * ldc + gc;
        if (EPI == 1 || EPI == 2) v += bsv;
        if (EPI == 2) v = 0.5f * v * (1.0f + erff(v * 0.70710678118654752f));
        if (EPI == 3) v += (float)(*cp);
        *cp = (TC)v;
      }
    }
  }
}

template <bool BT, int EPI, typename TC>
static void mg(const float* A, int lda, const float* Bw, int ldb,
               const float* bias, void* C, int ldc,
               int M, int N, int K, hipStream_t s) {
  dim3 g(M / 64, N / 64);
  mgemm_kernel<BT, EPI, TC><<<g, 256, 0, s>>>(A, lda, Bw, ldb, bias,
                                              (TC*)C, ldc, M, N, K);
}

// ---------------- heatmap precompute (bf16) ----------------

__global__ __launch_bounds__(256) void nodehm_kernel(const float* __restrict__ boxes,
                                                     bf16* __restrict__ hm) {
  int t = blockIdx.x;
  float cx = clampf(boxes[t * 4 + 0], -10.f, 10.f);
  float cy = clampf(boxes[t * 4 + 1], -10.f, 10.f);
  float w  = clampf(boxes[t * 4 + 2], -10.f, 10.f);
  float h  = clampf(boxes[t * 4 + 3], -10.f, 10.f);
  float dwx = w * w * 0.5f + 1e-6f;
  float dhy = h * h * 0.5f + 1e-6f;
  for (int pix = threadIdx.x; pix < HW_C; pix += 256) {
    int y = pix / 40, x = pix - y * 40;
    float gx = ((float)x + 0.5f) * 0.025f;
    float gy = ((float)y + 0.5f) * 0.025f;
    hm[(size_t)t * HW_C + pix] = __float2bfloat16(
        expf(-(gx - cx) * (gx - cx) / dwx) * expf(-(gy - cy) * (gy - cy) / dhy));
  }
}

__global__ __launch_bounds__(256) void edgehm_kernel(const float* __restrict__ boxes,
                                                     const int* __restrict__ el,
                                                     const bf16* __restrict__ nhm,
                                                     bf16* __restrict__ ehm) {
  int e = blockIdx.x;
  int b = e >> 6;
  int sg = clampi(el[e], 0, N_C - 1) + b * N_C;
  int dg = clampi(el[TE_C + e], 0, N_C - 1) + b * N_C;
  float c1x = clampf(boxes[sg * 4 + 0], -10.f, 10.f);
  float c1y = clampf(boxes[sg * 4 + 1], -10.f, 10.f);
  float w1  = clampf(boxes[sg * 4 + 2], -10.f, 10.f);
  float h1  = clampf(boxes[sg * 4 + 3], -10.f, 10.f);
  float c2x = clampf(boxes[dg * 4 + 0], -10.f, 10.f);
  float c2y = clampf(boxes[dg * 4 + 1], -10.f, 10.f);
  float w2  = clampf(boxes[dg * 4 + 2], -10.f, 10.f);
  float h2  = clampf(boxes[dg * 4 + 3], -10.f, 10.f);
  float ux1 = fminf(c1x - w1 * 0.5f, c2x - w2 * 0.5f);
  float uy1 = fminf(c1y - h1 * 0.5f, c2y - h2 * 0.5f);
  float ux2 = fmaxf(c1x + w1 * 0.5f, c2x + w2 * 0.5f);
  float uy2 = fmaxf(c1y + h1 * 0.5f, c2y + h2 * 0.5f);
  float cx = 0.5f * (ux1 + ux2), cy = 0.5f * (uy1 + uy2);
  float w = ux2 - ux1, h = uy2 - uy1;
  float dwx = w * w * 0.5f + 1e-6f;
  float dhy = h * h * 0.5f + 1e-6f;
  for (int pix = threadIdx.x; pix < HW_C; pix += 256) {
    int y = pix / 40, x = pix - y * 40;
    float gx = ((float)x + 0.5f) * 0.025f;
    float gy = ((float)y + 0.5f) * 0.025f;
    float u = expf(-(gx - cx) * (gx - cx) / dwx) * expf(-(gy - cy) * (gy - cy) / dhy);
    float v = fmaxf(fmaxf(bf2f(nhm[(size_t)sg * HW_C + pix]),
                          bf2f(nhm[(size_t)dg * HW_C + pix])), u);
    ehm[(size_t)e * HW_C + pix] = __float2bfloat16(v);
  }
}

// ---------------- precompute kernels ----------------

__global__ __launch_bounds__(256) void embq_kernel(const float* __restrict__ boxes,
                                                   const int* __restrict__ el,
                                                   bf16* __restrict__ emb) {
  int t = blockIdx.x;
  int d = threadIdx.x;
  int c = d >> 6, inner = d & 63;
  float v;
  if (t < TN_C) {
    v = boxes[t * 4 + c];
  } else {
    int e = t - TN_C;
    int b = e >> 6;
    int sg = clampi(el[e], 0, N_C - 1) + b * N_C;
    int dg = clampi(el[TE_C + e], 0, N_C - 1) + b * N_C;
    v = boxes[sg * 4 + c] - boxes[dg * 4 + c];
  }
  v = clampf(v, -100.f, 100.f);
  int i = inner & 31;
  float freq = expf(-9.210340371976184f * (float)i / 32.0f);
  float ang = v * freq;
  emb[(size_t)t * D_C + d] = __float2bfloat16((inner < 32) ? sinf(ang) : cosf(ang));
}

__global__ __launch_bounds__(256) void initq_kernel(const float* __restrict__ nodes0,
                                                    const float* __restrict__ edges0,
                                                    float* __restrict__ q) {
  int idx = blockIdx.x * 256 + threadIdx.x;
  int t = idx >> 8;
  q[idx] = (t < TN_C) ? nodes0[idx] : edges0[idx - TN_C * D_C];
}

// ---------------- LayerNorm (optionally writes xe = x + emb) ---------------

__global__ __launch_bounds__(256) void ln_kernel(const float* __restrict__ qin,
                                                 const float* __restrict__ g,
                                                 const float* __restrict__ bb,
                                                 float* __restrict__ xout,
                                                 const bf16* __restrict__ emb,
                                                 float* __restrict__ xeout) {
  __shared__ float red[4];
  int r = blockIdx.x, tid = threadIdx.x;
  size_t base = (size_t)r * D_C;
  float v = qin[base + tid];
  float s = v;
#pragma unroll
  for (int o = 1; o < 64; o <<= 1) s += __shfl_xor(s, o);
  if ((tid & 63) == 0) red[tid >> 6] = s;
  __syncthreads();
  float mean = (red[0] + red[1] + red[2] + red[3]) * (1.0f / 256.0f);
  __syncthreads();
  float d = v - mean;
  float s2 = d * d;
#pragma unroll
  for (int o = 1; o < 64; o <<= 1) s2 += __shfl_xor(s2, o);
  if ((tid & 63) == 0) red[tid >> 6] = s2;
  __syncthreads();
  float var = (red[0] + red[1] + red[2] + red[3]) * (1.0f / 256.0f);
  float xo = d * rsqrtf(var + 1e-5f) * g[tid] + bb[tid];
  xout[base + tid] = xo;
  if (xeout) xeout[base + tid] = xo + bf2f(emb[base + tid]);
}

// ---------------- attention: one wave per (token-in-launch, head) ----------
// KV: (nb*HW, 512) bf16 for batches [c0, c0+nb). cols 0..255 K, 256..511 V.
// HM=true: bias read from precomputed bf16 heatmaps; else on-the-fly gauss.

template <bool HM>
__global__ __launch_bounds__(256) void attn_kernel(const float* __restrict__ Qp,
                                                   const bf16* __restrict__ KV,
                                                   const bf16* __restrict__ nhm,
                                                   const bf16* __restrict__ ehm,
                                                   const float* __restrict__ boxes,
                                                   const int* __restrict__ el,
                                                   int c0, int nb,
                                                   float* __restrict__ O) {
  int wid = threadIdx.x >> 6;
  int lane = threadIdx.x & 63;
  int gw = blockIdx.x * 4 + wid;
  int tic = gw >> 3, h = gw & 7;
  int t, bl, nG = 0;
  const bf16* brow = nullptr;
  float pcx[3], pcy[3], pdx[3], pdy[3];
  if (tic < nb * N_C) {                    // node token
    bl = tic >> 5;
    t = (c0 + bl) * N_C + (tic & 31);
    if (HM) {
      brow = nhm + (size_t)t * HW_C;
    } else {
      float cx = clampf(boxes[t * 4 + 0], -10.f, 10.f);
      float cy = clampf(boxes[t * 4 + 1], -10.f, 10.f);
      float w  = clampf(boxes[t * 4 + 2], -10.f, 10.f);
      float hh = clampf(boxes[t * 4 + 3], -10.f, 10.f);
      pcx[0] = cx; pcy[0] = cy;
      pdx[0] = w * w * 0.5f + 1e-6f; pdy[0] = hh * hh * 0.5f + 1e-6f;
      nG = 1;
    }
  } else {                                 // edge token
    int ei = tic - nb * N_C;
    bl = ei >> 6;
    int e = (c0 + bl) * E_C + (ei & 63);
    t = TN_C + e;
    if (HM) {
      brow = ehm + (size_t)e * HW_C;
    } else {
      int sg = clampi(el[e], 0, N_C - 1) + (c0 + bl) * N_C;
      int dg = clampi(el[TE_C + e], 0, N_C - 1) + (c0 + bl) * N_C;
      float c1x = clampf(boxes[sg * 4 + 0], -10.f, 10.f);
      float c1y = clampf(boxes[sg * 4 + 1], -10.f, 10.f);
      float w1  = clampf(boxes[sg * 4 + 2], -10.f, 10.f);
      float h1  = clampf(boxes[sg * 4 + 3], -10.f, 10.f);
      float c2x = clampf(boxes[dg * 4 + 0], -10.f, 10.f);
      float c2y = clampf(boxes[dg * 4 + 1], -10.f, 10.f);
      float w2  = clampf(boxes[dg * 4 + 2], -10.f, 10.f);
      float h2  = clampf(boxes[dg * 4 + 3], -10.f, 10.f);
      pcx[0] = c1x; pcy[0] = c1y;
      pdx[0] = w1 * w1 * 0.5f + 1e-6f; pdy[0] = h1 * h1 * 0.5f + 1e-6f;
      pcx[1] = c2x; pcy[1] = c2y;
      pdx[1] = w2 * w2 * 0.5f + 1e-6f; pdy[1] = h2 * h2 * 0.5f + 1e-6f;
      float ux1 = fminf(c1x - w1 * 0.5f, c2x - w2 * 0.5f);
      float uy1 = fminf(c1y - h1 * 0.5f, c2y - h2 * 0.5f);
      float ux2 = fmaxf(c1x + w1 * 0.5f, c2x + w2 * 0.5f);
      float uy2 = fmaxf(c1y + h1 * 0.5f, c2y + h2 * 0.5f);
      float uw = ux2 - ux1, uh = uy2 - uy1;
      pcx[2] = 0.5f * (ux1 + ux2); pcy[2] = 0.5f * (uy1 + uy2);
      pdx[2] = uw * uw * 0.5f + 1e-6f; pdy[2] = uh * uh * 0.5f + 1e-6f;
      nG = 3;
    }
  }

  float qv[32];
  const float* qp = Qp + (size_t)t * D_C + h * DH_C;
#pragma unroll
  for (int d = 0; d < 32; d++) qv[d] = qp[d];

  const float scale = 0.17677669529663687f;  // 1/sqrt(32)
  const bf16* kvb = KV + (size_t)bl * HW_C * 512 + h * DH_C;

  float sarr[25];
  float m = -1e30f;
#pragma unroll
  for (int i = 0; i < 25; i++) {
    int kk = lane + i * 64;
    float kf[32];
    load_bf16x32(kvb + (size_t)kk * 512, kf);
    float s = 0.f;
#pragma unroll
    for (int d = 0; d < 32; d++) s = fmaf(kf[d], qv[d], s);
    float bias;
    if (HM) {
      bias = bf2f(brow[kk]);
    } else {
      int yy = kk / 40, xx = kk - yy * 40;
      float gx = ((float)xx + 0.5f) * 0.025f;
      float gy = ((float)yy + 0.5f) * 0.025f;
      bias = 0.f;
      for (int g = 0; g < nG; g++) {
        float dxv = gx - pcx[g], dyv = gy - pcy[g];
        float e = expf(-dxv * dxv / pdx[g]) * expf(-dyv * dyv / pdy[g]);
        bias = fmaxf(bias, e);
      }
    }
    s = clampf(s * scale + bias, -1e30f, 1e30f);
    sarr[i] = s;
    m = fmaxf(m, s);
  }
#pragma unroll
  for (int o = 1; o < 64; o <<= 1) m = fmaxf(m, __shfl_xor(m, o));

  float l = 0.f;
  float acc[32] = {};
#pragma unroll
  for (int i = 0; i < 25; i++) {
    int kk = lane + i * 64;
    float vf[32];
    load_bf16x32(kvb + (size_t)kk * 512 + 256, vf);
    float e = expf(fminf(sarr[i] - m, 0.f));
    l += e;
#pragma unroll
    for (int d = 0; d < 32; d++) acc[d] = fmaf(e, vf[d], acc[d]);
  }
#pragma unroll
  for (int o = 1; o < 64; o <<= 1) {
    l += __shfl_xor(l, o);
#pragma unroll
    for (int d = 0; d < 32; d++) acc[d] += __shfl_xor(acc[d], o);
  }
  if (lane == 0) {
    float inv = 1.0f / fmaxf(l, 1e-30f);
    float* op = O + (size_t)t * D_C + h * DH_C;
#pragma unroll
    for (int d = 0; d < 32; d++) op[d] = acc[d] * inv;
  }
}

// ---------------- GAT kernels ----------------

__global__ __launch_bounds__(256) void gat_logits_kernel(const float* __restrict__ hee,
                                                         const int* __restrict__ el,
                                                         const float* __restrict__ as,
                                                         const float* __restrict__ ad,
                                                         const float* __restrict__ ae,
                                                         float* __restrict__ logits) {
  int idx = blockIdx.x * 256 + threadIdx.x;  // Te*NH
  int e = idx >> 3, h = idx & 7;
  int b = e >> 6;
  int sg = clampi(el[e], 0, N_C - 1) + b * N_C;
  int dg = clampi(el[TE_C + e], 0, N_C - 1) + b * N_C;
  const float* hs = hee + (size_t)sg * D_C + h * DH_C;
  const float* hd = hee + (size_t)dg * D_C + h * DH_C;
  const float* ep = hee + (size_t)(TN_C + e) * D_C + h * DH_C;
  float s = 0.f;
#pragma unroll
  for (int d = 0; d < 32; d++) {
    s += hs[d] * as[h * 32 + d] + hd[d] * ad[h * 32 + d] + ep[d] * ae[h * 32 + d];
  }
  s = clampf(s, -1e30f, 1e30f);
  logits[idx] = (s > 0.f) ? s : 0.2f * s;
}

__global__ __launch_bounds__(256) void gat_mden_kernel(const float* __restrict__ logits,
                                                       const int* __restrict__ el,
                                                       float* __restrict__ mb,
                                                       float* __restrict__ db) {
  int idx = blockIdx.x * 256 + threadIdx.x;  // Tn*NH
  int n = idx >> 3, h = idx & 7;
  int b = n >> 5;
  int e0 = b * E_C;
  float m = -1e30f;
  for (int k = 0; k < 64; k++) {
    int dg = clampi(el[TE_C + e0 + k], 0, N_C - 1) + b * N_C;
    if (dg == n) m = fmaxf(m, logits[(e0 + k) * 8 + h]);
  }
  float den = 0.f;
  for (int k = 0; k < 64; k++) {
    int dg = clampi(el[TE_C + e0 + k], 0, N_C - 1) + b * N_C;
    if (dg == n) den += expf(fminf(logits[(e0 + k) * 8 + h] - m, 0.f));
  }
  mb[idx] = m;
  db[idx] = den;
}

__global__ __launch_bounds__(256) void gat_alpha_kernel(const float* __restrict__ logits,
                                                        const int* __restrict__ el,
                                                        const float* __restrict__ mb,
                                                        const float* __restrict__ db,
                                                        float* __restrict__ al) {
  int idx = blockIdx.x * 256 + threadIdx.x;  // Te*NH
  int e = idx >> 3, h = idx & 7;
  int b = e >> 6;
  int dg = clampi(el[TE_C + e], 0, N_C - 1) + b * N_C;
  float ex = expf(fminf(logits[idx] - mb[dg * 8 + h], 0.f));
  al[idx] = ex / (db[dg * 8 + h] + 1e-9f);
}

__global__ __launch_bounds__(256) void gat_nout_kernel(const float* __restrict__ hee,
                                                       const int* __restrict__ el,
                                                       const float* __restrict__ al,
                                                       float* __restrict__ noutp) {
  int n = blockIdx.x, d = threadIdx.x;
  int h = d >> 5;
  int b = n >> 5;
  int e0 = b * E_C;
  float acc = 0.f;
  for (int k = 0; k < 64; k++) {
    int e = e0 + k;
    int dg = clampi(el[TE_C + e], 0, N_C - 1) + b * N_C;
    if (dg == n) {
      int sg = clampi(el[e], 0, N_C - 1) + b * N_C;
      acc += al[e * 8 + h] * (hee[(size_t)sg * D_C + d] + hee[(size_t)(TN_C + e) * D_C + d]);
    }
  }
  noutp[(size_t)n * D_C + d] = acc;
}

// ---------------- elementwise residual kernels ----------------

__global__ __launch_bounds__(256) void axpy_kernel(float* __restrict__ q,
                                                   const float* __restrict__ delta,
                                                   const float* __restrict__ ls) {
  int idx = blockIdx.x * 256 + threadIdx.x;
  q[idx] += ls[idx & 255] * delta[idx];
}

__global__ __launch_bounds__(256) void axpy_store_kernel(float* __restrict__ q,
                                                         const float* __restrict__ delta,
                                                         const float* __restrict__ ls,
                                                         float* __restrict__ out) {
  int idx = blockIdx.x * 256 + threadIdx.x;
  float v = q[idx] + ls[idx & 255] * delta[idx];
  q[idx] = v;
  out[idx] = v;
}

__global__ __launch_bounds__(256) void base_add_kernel(float* __restrict__ q,
                                                       const float* __restrict__ xbase,
                                                       const float* __restrict__ delta,
                                                       const float* __restrict__ ls) {
  int idx = blockIdx.x * 256 + threadIdx.x;
  q[idx] = xbase[idx] + ls[idx & 255] * delta[idx];
}

// Final pass: kill NaN/inf so corruption yields a finite diagnostic absmax.
__global__ __launch_bounds__(256) void sanitize_kernel(float* __restrict__ out) {
  int idx = blockIdx.x * 256 + threadIdx.x;
  float v = out[idx];
  if (!(fabsf(v) <= 1e4f)) out[idx] = 0.f;
}

// ---------------- host ----------------

extern "C" void kernel_launch(void* const* d_in, const int* in_sizes, int n_in,
                              void* d_out, int out_size, void* d_ws, size_t ws_size,
                              hipStream_t stream) {
  const float* features   = (const float*)d_in[0];
  const float* boxes      = (const float*)d_in[1];
  const int*   edge_local = (const int*)d_in[2];
  const float* nodes0     = (const float*)d_in[3];
  const float* edges0     = (const float*)d_in[4];
  const float* ln1_g      = (const float*)d_in[5];
  const float* ln1_b      = (const float*)d_in[6];
  const float* attn_in_w  = (const float*)d_in[7];
  const float* attn_in_b  = (const float*)d_in[8];
  const float* attn_out_w = (const float*)d_in[9];
  const float* attn_out_b = (const float*)d_in[10];
  const float* ls1        = (const float*)d_in[11];
  const float* ln2_g      = (const float*)d_in[12];
  const float* ln2_b      = (const float*)d_in[13];
  const float* gat_wn     = (const float*)d_in[14];
  const float* gat_we     = (const float*)d_in[15];
  const float* gat_a_src  = (const float*)d_in[16];
  const float* gat_a_dst  = (const float*)d_in[17];
  const float* gat_a_edge = (const float*)d_in[18];
  const float* gat_wo     = (const float*)d_in[19];
  const float* gat_bo     = (const float*)d_in[20];
  const float* gat_woe    = (const float*)d_in[21];
  const float* gat_boe    = (const float*)d_in[22];
  const float* ls2        = (const float*)d_in[23];
  const float* ln3_g      = (const float*)d_in[24];
  const float* ln3_b      = (const float*)d_in[25];
  const float* ffn_w1     = (const float*)d_in[26];
  const float* ffn_b1     = (const float*)d_in[27];
  const float* ffn_w2     = (const float*)d_in[28];
  const float* ffn_b2     = (const float*)d_in[29];
  const float* ls3        = (const float*)d_in[30];
  float* out = (float*)d_out;

  size_t off = 0;
  auto alloc = [&](size_t bytes) -> void* {
    void* p = (char*)d_ws + off;
    off += (bytes + 255) & ~(size_t)255;
    return p;
  };
  const size_t TD = (size_t)TT_C * D_C;
  bf16*  emb   = (bf16*)alloc(TD * 2);
  float* q     = (float*)alloc(TD * 4);
  float* t0    = (float*)alloc(TD * 4);
  float* t1    = (float*)alloc(TD * 4);
  float* ybig  = (float*)alloc((size_t)TT_C * 512 * 4);
  float* logits= (float*)alloc((size_t)TE_C * 8 * 4);
  float* mb    = (float*)alloc((size_t)TN_C * 8 * 4);
  float* db    = (float*)alloc((size_t)TN_C * 8 * 4);
  float* al    = (float*)alloc((size_t)TE_C * 8 * 4);
  float* hee   = ybig;
  float* noutp = ybig + (size_t)TT_C * 256;

  const size_t KV_FULL = (size_t)B_C * HW_C * 512 * 2;   // 52.43 MB
  const size_t KV_CHNK = (size_t)4 * HW_C * 512 * 2;     // 6.55 MB
  const size_t HM_SZ   = (size_t)(TN_C + TE_C) * HW_C * 2; // 9.83 MB
  // mode 2: full KV + heatmaps; 1: chunked KV + heatmaps; 0: chunked, no HM
  int mode;
  if (ws_size >= off + KV_FULL + HM_SZ + (1 << 20)) mode = 2;
  else if (ws_size >= off + KV_CHNK + HM_SZ + (1 << 20)) mode = 1;
  else mode = 0;
  bf16* KV = (bf16*)alloc(mode == 2 ? KV_FULL : KV_CHNK);
  bf16 *nhm = nullptr, *ehm = nullptr;
  if (mode >= 1) {
    nhm = (bf16*)alloc((size_t)TN_C * HW_C * 2);
    ehm = (bf16*)alloc((size_t)TE_C * HW_C * 2);
  }
  (void)in_sizes; (void)n_in; (void)out_size;

  // precompute
  embq_kernel<<<TT_C, 256, 0, stream>>>(boxes, edge_local, emb);
  initq_kernel<<<TT_C, 256, 0, stream>>>(nodes0, edges0, q);
  if (mode >= 1) {
    nodehm_kernel<<<TN_C, 256, 0, stream>>>(boxes, nhm);
    edgehm_kernel<<<TE_C, 256, 0, stream>>>(boxes, edge_local, nhm, ehm);
  }

  for (int l = 0; l < L_C; l++) {
    const float* Wq  = attn_in_w + (size_t)l * 768 * 256;
    const float* WKV = Wq + (size_t)256 * 256;
    const float* bq  = attn_in_b + (size_t)l * 768;
    const float* bKV = bq + 256;

    // LN1: q -> t0
    ln_kernel<<<TT_C, 256, 0, stream>>>(q, ln1_g + l * 256, ln1_b + l * 256,
                                        t0, nullptr, nullptr);
    // Q projection: t0 @ Wq^T + bq -> t1
    mg<true, 1, float>(t0, 256, Wq, 256, bq, t1, 256, TT_C, 256, 256, stream);
    // K/V projection + attention (attn writes o into t0)
    if (mode == 2) {
      mg<true, 1, bf16>(features, 256, WKV, 256, bKV, KV, 512,
                        B_C * HW_C, 512, 256, stream);
      attn_kernel<true><<<B_C * 192, 256, 0, stream>>>(
          t1, KV, nhm, ehm, boxes, edge_local, 0, B_C, t0);
    } else {
      for (int c = 0; c < B_C / 4; c++) {
        mg<true, 1, bf16>(features + (size_t)c * 4 * HW_C * 256, 256,
                          WKV, 256, bKV, KV, 512, 4 * HW_C, 512, 256, stream);
        if (mode == 1)
          attn_kernel<true><<<4 * 192, 256, 0, stream>>>(
              t1, KV, nhm, ehm, boxes, edge_local, c * 4, 4, t0);
        else
          attn_kernel<false><<<4 * 192, 256, 0, stream>>>(
              t1, KV, nhm, ehm, boxes, edge_local, c * 4, 4, t0);
      }
    }
    // output projection: t0 @ Wo^T + bo -> t1
    mg<true, 1, float>(t0, 256, attn_out_w + (size_t)l * 65536, 256,
                       attn_out_b + l * 256, t1, 256, TT_C, 256, 256, stream);
    // q += ls1 * t1
    axpy_kernel<<<TT_C, 256, 0, stream>>>(q, t1, ls1 + l * 256);
    // LN2: q -> x2=t0, xe=t1
    ln_kernel<<<TT_C, 256, 0, stream>>>(q, ln2_g + l * 256, ln2_b + l * 256,
                                        t0, emb, t1);
    // GAT projections -> hee
    mg<false, 0, float>(t1, 256, gat_wn + (size_t)l * 65536, 256,
                        nullptr, hee, 256, TN_C, 256, 256, stream);
    mg<false, 0, float>(t1 + (size_t)TN_C * 256, 256,
                        gat_we + (size_t)l * 65536, 256, nullptr,
                        hee + (size_t)TN_C * 256, 256, TE_C, 256, 256, stream);
    // GAT attention
    gat_logits_kernel<<<(TE_C * 8) / 256, 256, 0, stream>>>(
        hee, edge_local, gat_a_src + l * 256, gat_a_dst + l * 256,
        gat_a_edge + l * 256, logits);
    gat_mden_kernel<<<(TN_C * 8) / 256, 256, 0, stream>>>(logits, edge_local, mb, db);
    gat_alpha_kernel<<<(TE_C * 8) / 256, 256, 0, stream>>>(logits, edge_local, mb, db, al);
    gat_nout_kernel<<<TN_C, 256, 0, stream>>>(hee, edge_local, al, noutp);
    // GAT output projections -> t1
    mg<false, 1, float>(noutp, 256, gat_wo + (size_t)l * 65536, 256,
                        gat_bo + l * 256, t1, 256, TN_C, 256, 256, stream);
    mg<false, 1, float>(hee + (size_t)TN_C * 256, 256,
                        gat_woe + (size_t)l * 65536, 256,
                        gat_boe + l * 256, t1 + (size_t)TN_C * 256, 256,
                        TE_C, 256, 256, stream);
    // q = x2(t0) + ls2 * t1
    base_add_kernel<<<TT_C, 256, 0, stream>>>(q, t0, t1, ls2 + l * 256);
    // LN3: q -> t0
    ln_kernel<<<TT_C, 256, 0, stream>>>(q, ln3_g + l * 256, ln3_b + l * 256,
                                        t0, nullptr, nullptr);
    // FFN in two 512-wide halves through ybig
    const float* W1 = ffn_w1 + (size_t)l * 262144;
    const float* W2 = ffn_w2 + (size_t)l * 262144;
    mg<false, 2, float>(t0, 256, W1, 1024, ffn_b1 + l * 1024,
                        ybig, 512, TT_C, 512, 256, stream);
    mg<false, 1, float>(ybig, 512, W2, 256, ffn_b2 + l * 256,
                        t1, 256, TT_C, 256, 512, stream);
    mg<false, 2, float>(t0, 256, W1 + 512, 1024, ffn_b1 + l * 1024 + 512,
                        ybig, 512, TT_C, 512, 256, stream);
    mg<false, 3, float>(ybig, 512, W2 + (size_t)512 * 256, 256,
                        nullptr, t1, 256, TT_C, 256, 512, stream);
    // q += ls3 * t1 ; store layer output
    axpy_store_kernel<<<TT_C, 256, 0, stream>>>(q, t1, ls3 + l * 256,
                                                out + (size_t)l * TD);
  }
  sanitize_kernel<<<(L_C * (int)TD) / 256, 256, 0, stream>>>(out);
}

// Round 6
// 2149.048 us; speedup vs baseline: 4.2617x; 3.0384x over previous
//
#include <hip/hip_runtime.h>
#include <hip/hip_bf16.h>
#include <math.h>

typedef __hip_bfloat16 bf16;
typedef unsigned short ushort_t;
typedef __attribute__((ext_vector_type(8))) short bf16x8;
typedef __attribute__((ext_vector_type(4))) float f32x4;

static constexpr int B_C   = 32;
static constexpr int N_C   = 32;
static constexpr int E_C   = 64;
static constexpr int HW_C  = 1600;
static constexpr int D_C   = 256;
static constexpr int NH_C  = 8;
static constexpr int DH_C  = 32;
static constexpr int L_C   = 6;
static constexpr int TN_C  = 1024;   // B*N
static constexpr int TE_C  = 2048;   // B*E
static constexpr int TT_C  = 3072;   // TN+TE

__device__ __forceinline__ float bf2f(bf16 v) { return __bfloat162float(v); }
__device__ __forceinline__ int clampi(int v, int lo, int hi) {
  return v < lo ? lo : (v > hi ? hi : v);
}
__device__ __forceinline__ float clampf(float v, float lo, float hi) {
  return fminf(fmaxf(v, lo), hi);
}
__device__ __forceinline__ ushort_t f2b(float x) {
  bf16 h = __float2bfloat16(x);
  return *reinterpret_cast<ushort_t*>(&h);
}

__device__ __forceinline__ void unpack_bf2(unsigned v, float& a, float& b) {
  union { unsigned u; float f; } ua, ub;
  ua.u = v << 16;
  ub.u = v & 0xffff0000u;
  a = ua.f; b = ub.f;
}

__device__ __forceinline__ void load_bf16x32(const bf16* p, float* out) {
  const uint4* p4 = reinterpret_cast<const uint4*>(p);
#pragma unroll
  for (int w = 0; w < 4; w++) {
    uint4 u = p4[w];
    unpack_bf2(u.x, out[w * 8 + 0], out[w * 8 + 1]);
    unpack_bf2(u.y, out[w * 8 + 2], out[w * 8 + 3]);
    unpack_bf2(u.z, out[w * 8 + 4], out[w * 8 + 5]);
    unpack_bf2(u.w, out[w * 8 + 6], out[w * 8 + 7]);
  }
}

// ============ MFMA bf16 GEMM: C(M,N) = A(M,K)@B (+epilogue) ===============
static constexpr int SA = 40;  // LDS row stride in shorts

__device__ __forceinline__ void stage8(const float* __restrict__ src,
                                       ushort_t* __restrict__ dst) {
  float4 f0 = *(const float4*)src;
  float4 f1 = *(const float4*)(src + 4);
  ushort_t t[8] = { f2b(f0.x), f2b(f0.y), f2b(f0.z), f2b(f0.w),
                    f2b(f1.x), f2b(f1.y), f2b(f1.z), f2b(f1.w) };
  *(uint4*)dst = *(const uint4*)t;
}

template <bool BT, int EPI, typename TC>
__global__ __launch_bounds__(256) void mgemm_kernel(
    const float* __restrict__ A, int lda, const float* __restrict__ Bw, int ldb,
    const float* __restrict__ bias, TC* __restrict__ C, int ldc,
    int M, int N, int K)
{
  __shared__ ushort_t As[64 * SA];
  __shared__ ushort_t Bs[64 * SA];
  const int tid = threadIdx.x;
  const int row0 = blockIdx.x * 64, col0 = blockIdx.y * 64;
  const int wave = tid >> 6, lane = tid & 63;
  const int wm = (wave >> 1) * 32, wn = (wave & 1) * 32;
  const int lm = lane & 15, quad = lane >> 4;

  f32x4 acc[2][2] = {};

  const int am = tid >> 2, akk = (tid & 3) * 8;
  const int bn = tid & 63, bkb = (tid >> 6) * 8;

  for (int k0 = 0; k0 < K; k0 += 32) {
    stage8(A + (size_t)(row0 + am) * lda + k0 + akk, &As[am * SA + akk]);
    if (BT) {
      stage8(Bw + (size_t)(col0 + am) * ldb + k0 + akk, &Bs[am * SA + akk]);
    } else {
      ushort_t t[8];
#pragma unroll
      for (int j = 0; j < 8; j++)
        t[j] = f2b(Bw[(size_t)(k0 + bkb + j) * ldb + col0 + bn]);
      *(uint4*)(&Bs[bn * SA + bkb]) = *(const uint4*)t;
    }
    __syncthreads();
    bf16x8 a0 = *(const bf16x8*)(&As[(wm + lm) * SA + quad * 8]);
    bf16x8 a1 = *(const bf16x8*)(&As[(wm + 16 + lm) * SA + quad * 8]);
    bf16x8 b0 = *(const bf16x8*)(&Bs[(wn + lm) * SA + quad * 8]);
    bf16x8 b1 = *(const bf16x8*)(&Bs[(wn + 16 + lm) * SA + quad * 8]);
    acc[0][0] = __builtin_amdgcn_mfma_f32_16x16x32_bf16(a0, b0, acc[0][0], 0, 0, 0);
    acc[0][1] = __builtin_amdgcn_mfma_f32_16x16x32_bf16(a0, b1, acc[0][1], 0, 0, 0);
    acc[1][0] = __builtin_amdgcn_mfma_f32_16x16x32_bf16(a1, b0, acc[1][0], 0, 0, 0);
    acc[1][1] = __builtin_amdgcn_mfma_f32_16x16x32_bf16(a1, b1, acc[1][1], 0, 0, 0);
    __syncthreads();
  }

#pragma unroll
  for (int ti = 0; ti < 2; ti++) {
#pragma unroll
    for (int tj = 0; tj < 2; tj++) {
      int gc = col0 + wn + tj * 16 + lm;
      float bsv = (EPI == 1 || EPI == 2) ? bias[gc] : 0.f;
#pragma unroll
      for (int r = 0; r < 4; r++) {
        int gr = row0 + wm + ti * 16 + quad * 4 + r;
        float v = acc[ti][tj][r];
        TC* cp = C + (size_t)gr * ldc + gc;
        if (EPI == 1 || EPI == 2) v += bsv;
        if (EPI == 2) v = 0.5f * v * (1.0f + erff(v * 0.70710678118654752f));
        if (EPI == 3) v += (float)(*cp);
        *cp = (TC)v;
      }
    }
  }
}

template <bool BT, int EPI, typename TC>
static void mg(const float* A, int lda, const float* Bw, int ldb,
               const float* bias, void* C, int ldc,
               int M, int N, int K, hipStream_t s) {
  dim3 g(M / 64, N / 64);
  mgemm_kernel<BT, EPI, TC><<<g, 256, 0, s>>>(A, lda, Bw, ldb, bias,
                                              (TC*)C, ldc, M, N, K);
}

// ---------------- heatmap precompute (bf16) ----------------

__global__ __launch_bounds__(256) void nodehm_kernel(const float* __restrict__ boxes,
                                                     bf16* __restrict__ hm) {
  int t = blockIdx.x;
  float cx = clampf(boxes[t * 4 + 0], -10.f, 10.f);
  float cy = clampf(boxes[t * 4 + 1], -10.f, 10.f);
  float w  = clampf(boxes[t * 4 + 2], -10.f, 10.f);
  float h  = clampf(boxes[t * 4 + 3], -10.f, 10.f);
  float dwx = w * w * 0.5f + 1e-6f;
  float dhy = h * h * 0.5f + 1e-6f;
  for (int pix = threadIdx.x; pix < HW_C; pix += 256) {
    int y = pix / 40, x = pix - y * 40;
    float gx = ((float)x + 0.5f) * 0.025f;
    float gy = ((float)y + 0.5f) * 0.025f;
    hm[(size_t)t * HW_C + pix] = __float2bfloat16(
        expf(-(gx - cx) * (gx - cx) / dwx) * expf(-(gy - cy) * (gy - cy) / dhy));
  }
}

__global__ __launch_bounds__(256) void edgehm_kernel(const float* __restrict__ boxes,
                                                     const int* __restrict__ el,
                                                     const bf16* __restrict__ nhm,
                                                     bf16* __restrict__ ehm) {
  int e = blockIdx.x;
  int b = e >> 6;
  int sg = clampi(el[e], 0, N_C - 1) + b * N_C;
  int dg = clampi(el[TE_C + e], 0, N_C - 1) + b * N_C;
  float c1x = clampf(boxes[sg * 4 + 0], -10.f, 10.f);
  float c1y = clampf(boxes[sg * 4 + 1], -10.f, 10.f);
  float w1  = clampf(boxes[sg * 4 + 2], -10.f, 10.f);
  float h1  = clampf(boxes[sg * 4 + 3], -10.f, 10.f);
  float c2x = clampf(boxes[dg * 4 + 0], -10.f, 10.f);
  float c2y = clampf(boxes[dg * 4 + 1], -10.f, 10.f);
  float w2  = clampf(boxes[dg * 4 + 2], -10.f, 10.f);
  float h2  = clampf(boxes[dg * 4 + 3], -10.f, 10.f);
  float ux1 = fminf(c1x - w1 * 0.5f, c2x - w2 * 0.5f);
  float uy1 = fminf(c1y - h1 * 0.5f, c2y - h2 * 0.5f);
  float ux2 = fmaxf(c1x + w1 * 0.5f, c2x + w2 * 0.5f);
  float uy2 = fmaxf(c1y + h1 * 0.5f, c2y + h2 * 0.5f);
  float cx = 0.5f * (ux1 + ux2), cy = 0.5f * (uy1 + uy2);
  float w = ux2 - ux1, h = uy2 - uy1;
  float dwx = w * w * 0.5f + 1e-6f;
  float dhy = h * h * 0.5f + 1e-6f;
  for (int pix = threadIdx.x; pix < HW_C; pix += 256) {
    int y = pix / 40, x = pix - y * 40;
    float gx = ((float)x + 0.5f) * 0.025f;
    float gy = ((float)y + 0.5f) * 0.025f;
    float u = expf(-(gx - cx) * (gx - cx) / dwx) * expf(-(gy - cy) * (gy - cy) / dhy);
    float v = fmaxf(fmaxf(bf2f(nhm[(size_t)sg * HW_C + pix]),
                          bf2f(nhm[(size_t)dg * HW_C + pix])), u);
    ehm[(size_t)e * HW_C + pix] = __float2bfloat16(v);
  }
}

// ---------------- precompute kernels ----------------

__global__ __launch_bounds__(256) void embq_kernel(const float* __restrict__ boxes,
                                                   const int* __restrict__ el,
                                                   bf16* __restrict__ emb) {
  int t = blockIdx.x;
  int d = threadIdx.x;
  int c = d >> 6, inner = d & 63;
  float v;
  if (t < TN_C) {
    v = boxes[t * 4 + c];
  } else {
    int e = t - TN_C;
    int b = e >> 6;
    int sg = clampi(el[e], 0, N_C - 1) + b * N_C;
    int dg = clampi(el[TE_C + e], 0, N_C - 1) + b * N_C;
    v = boxes[sg * 4 + c] - boxes[dg * 4 + c];
  }
  v = clampf(v, -100.f, 100.f);
  int i = inner & 31;
  float freq = expf(-9.210340371976184f * (float)i / 32.0f);
  float ang = v * freq;
  emb[(size_t)t * D_C + d] = __float2bfloat16((inner < 32) ? sinf(ang) : cosf(ang));
}

__global__ __launch_bounds__(256) void initq_kernel(const float* __restrict__ nodes0,
                                                    const float* __restrict__ edges0,
                                                    float* __restrict__ q) {
  int idx = blockIdx.x * 256 + threadIdx.x;
  int t = idx >> 8;
  q[idx] = (t < TN_C) ? nodes0[idx] : edges0[idx - TN_C * D_C];
}

// -------- LayerNorm with optional fused residual-add + xe output ----------
// v = base[i] (+ ls[d]*delta[i]); optionally qsave[i]=v; LN(v) -> xout;
// optionally xeout = LN + emb.

__global__ __launch_bounds__(256) void ln_kernel(const float* __restrict__ base,
                                                 const float* __restrict__ delta,
                                                 const float* __restrict__ ls,
                                                 float* __restrict__ qsave,
                                                 const float* __restrict__ g,
                                                 const float* __restrict__ bb,
                                                 float* __restrict__ xout,
                                                 const bf16* __restrict__ emb,
                                                 float* __restrict__ xeout) {
  __shared__ float red[4];
  int r = blockIdx.x, tid = threadIdx.x;
  size_t bofs = (size_t)r * D_C;
  float v = base[bofs + tid];
  if (delta) v += ls[tid] * delta[bofs + tid];
  if (qsave) qsave[bofs + tid] = v;
  float s = v;
#pragma unroll
  for (int o = 1; o < 64; o <<= 1) s += __shfl_xor(s, o);
  if ((tid & 63) == 0) red[tid >> 6] = s;
  __syncthreads();
  float mean = (red[0] + red[1] + red[2] + red[3]) * (1.0f / 256.0f);
  __syncthreads();
  float d = v - mean;
  float s2 = d * d;
#pragma unroll
  for (int o = 1; o < 64; o <<= 1) s2 += __shfl_xor(s2, o);
  if ((tid & 63) == 0) red[tid >> 6] = s2;
  __syncthreads();
  float var = (red[0] + red[1] + red[2] + red[3]) * (1.0f / 256.0f);
  float xo = d * rsqrtf(var + 1e-5f) * g[tid] + bb[tid];
  xout[bofs + tid] = xo;
  if (xeout) xeout[bofs + tid] = xo + bf2f(emb[bofs + tid]);
}

// ============ flash MFMA attention: one wg per (batch, head) ==============
// 192 threads = 3 waves; wave w owns query rows [w*32, w*32+32) of the 96
// tokens (32 nodes + 64 edges) of batch b. K/V staged in LDS in 160-key
// chunks; S via mfma; online softmax; P through LDS (bf16); PV via mfma.
static constexpr int ATK = 160;   // keys per chunk
static constexpr int KSTR = 40;   // K/V LDS row stride (shorts), 80B = 5x16
static constexpr int PSTR = 168;  // P LDS row stride (shorts), 336B = 21x16

__global__ __launch_bounds__(192) void fattn_kernel(const float* __restrict__ Qp,
                                                    const bf16* __restrict__ KV,
                                                    const bf16* __restrict__ nhm,
                                                    const bf16* __restrict__ ehm,
                                                    float* __restrict__ O) {
  __shared__ ushort_t Kl[ATK * KSTR];
  __shared__ ushort_t Vl[ATK * KSTR];
  __shared__ ushort_t Pl[3 * 32 * PSTR];

  const int b = blockIdx.x >> 3, h = blockIdx.x & 7;
  const int tid = threadIdx.x;
  const int wave = tid >> 6, lane = tid & 63;
  const int lm = lane & 15, quad = lane >> 4;
  const int wr0 = wave * 32;

  // token index + bias row per owned (mt, r): row = wr0 + mt*16 + quad*4 + r
  int tok[2][4];
  const bf16* brow[2][4];
#pragma unroll
  for (int mt = 0; mt < 2; mt++)
#pragma unroll
    for (int r = 0; r < 4; r++) {
      int row = wr0 + mt * 16 + quad * 4 + r;
      if (row < 32) {
        int t = b * N_C + row;
        tok[mt][r] = t; brow[mt][r] = nhm + (size_t)t * HW_C;
      } else {
        int e = b * E_C + (row - 32);
        tok[mt][r] = TN_C + e; brow[mt][r] = ehm + (size_t)e * HW_C;
      }
    }

  // Q A-frags (A[m=lm][k=quad*8+j]) for the wave's 2 row-tiles
  bf16x8 qa[2];
#pragma unroll
  for (int mt = 0; mt < 2; mt++) {
    int row = wr0 + mt * 16 + lm;
    int t = (row < 32) ? (b * N_C + row) : (TN_C + b * E_C + (row - 32));
    const float* qp = Qp + (size_t)t * D_C + h * DH_C + quad * 8;
    ushort_t tmp[8];
#pragma unroll
    for (int j = 0; j < 8; j++) tmp[j] = f2b(qp[j]);
    qa[mt] = *(const bf16x8*)tmp;
  }

  f32x4 Oacc[2][2] = {};
  float mrow[2][4], lrow[2][4];
#pragma unroll
  for (int mt = 0; mt < 2; mt++)
#pragma unroll
    for (int r = 0; r < 4; r++) { mrow[mt][r] = -1e30f; lrow[mt][r] = 0.f; }

  const bf16* kvb = KV + (size_t)b * HW_C * 512 + h * DH_C;  // K (V at +256)
  const float scale = 0.17677669529663687f;                  // 1/sqrt(32)
  ushort_t* Pw = &Pl[wave * 32 * PSTR];

  for (int k0 = 0; k0 < HW_C; k0 += ATK) {
    // stage K/V: 160 keys x 32 dims (4 chunks of 8 dims, 16B loads)
    for (int slot = tid; slot < ATK * 4; slot += 192) {
      int key = slot >> 2, dc = (slot & 3) * 8;
      const bf16* src = kvb + (size_t)(k0 + key) * 512 + dc;
      *(uint4*)&Kl[key * KSTR + dc] = *(const uint4*)src;
      *(uint4*)&Vl[key * KSTR + dc] = *(const uint4*)(src + 256);
    }
    __syncthreads();

    // S = Q @ K^T (C-layout: row=quad*4+r, key=lm within 16x16 tile)
    float s[2][10][4];
#pragma unroll
    for (int nt = 0; nt < 10; nt++) {
      bf16x8 kb = *(const bf16x8*)&Kl[(nt * 16 + lm) * KSTR + quad * 8];
#pragma unroll
      for (int mt = 0; mt < 2; mt++) {
        f32x4 d = {};
        d = __builtin_amdgcn_mfma_f32_16x16x32_bf16(qa[mt], kb, d, 0, 0, 0);
#pragma unroll
        for (int r = 0; r < 4; r++) s[mt][nt][r] = d[r];
      }
    }

    // bias + online softmax update
#pragma unroll
    for (int mt = 0; mt < 2; mt++)
#pragma unroll
      for (int r = 0; r < 4; r++) {
        const bf16* br = brow[mt][r] + k0 + lm;
        float mx = -1e30f;
#pragma unroll
        for (int nt = 0; nt < 10; nt++) {
          float v = s[mt][nt][r] * scale + bf2f(br[nt * 16]);
          s[mt][nt][r] = v;
          mx = fmaxf(mx, v);
        }
#pragma unroll
        for (int o = 1; o < 16; o <<= 1) mx = fmaxf(mx, __shfl_xor(mx, o));
        float mn = fmaxf(mrow[mt][r], mx);
        float lsum = 0.f;
        int prow = (mt * 16 + quad * 4 + r) * PSTR;
#pragma unroll
        for (int nt = 0; nt < 10; nt++) {
          float p = expf(fminf(s[mt][nt][r] - mn, 0.f));
          lsum += p;
          Pw[prow + nt * 16 + lm] = f2b(p);
        }
#pragma unroll
        for (int o = 1; o < 16; o <<= 1) lsum += __shfl_xor(lsum, o);
        float alpha = expf(fminf(mrow[mt][r] - mn, 0.f));
        lrow[mt][r] = lrow[mt][r] * alpha + lsum;
        mrow[mt][r] = mn;
        Oacc[mt][0][r] *= alpha;
        Oacc[mt][1][r] *= alpha;
      }

    // O += P @ V  (A = P from LDS, B = V[k=key][n=dim])
#pragma unroll
    for (int kc = 0; kc < 5; kc++) {
#pragma unroll
      for (int nt = 0; nt < 2; nt++) {
        ushort_t vb[8];
#pragma unroll
        for (int j = 0; j < 8; j++)
          vb[j] = Vl[(kc * 32 + quad * 8 + j) * KSTR + nt * 16 + lm];
        bf16x8 vfrag = *(const bf16x8*)vb;
#pragma unroll
        for (int mt = 0; mt < 2; mt++) {
          bf16x8 pa = *(const bf16x8*)&Pw[(mt * 16 + lm) * PSTR + kc * 32 + quad * 8];
          Oacc[mt][nt] = __builtin_amdgcn_mfma_f32_16x16x32_bf16(pa, vfrag,
                                                                 Oacc[mt][nt], 0, 0, 0);
        }
      }
    }
    __syncthreads();
  }

  // writeout (C-layout rows via quad/r, dims via lm)
#pragma unroll
  for (int mt = 0; mt < 2; mt++)
#pragma unroll
    for (int r = 0; r < 4; r++) {
      float inv = 1.0f / fmaxf(lrow[mt][r], 1e-30f);
      float* op = O + (size_t)tok[mt][r] * D_C + h * DH_C;
      op[lm]      = Oacc[mt][0][r] * inv;
      op[16 + lm] = Oacc[mt][1][r] * inv;
    }
}

// ------- legacy wave-per-(token,head) attention (small-ws fallback) -------

template <bool HM>
__global__ __launch_bounds__(256) void attn_kernel(const float* __restrict__ Qp,
                                                   const bf16* __restrict__ KV,
                                                   const bf16* __restrict__ nhm,
                                                   const bf16* __restrict__ ehm,
                                                   const float* __restrict__ boxes,
                                                   const int* __restrict__ el,
                                                   int c0, int nb,
                                                   float* __restrict__ O) {
  int wid = threadIdx.x >> 6;
  int lane = threadIdx.x & 63;
  int gw = blockIdx.x * 4 + wid;
  int tic = gw >> 3, h = gw & 7;
  int t, bl, nG = 0;
  const bf16* brow = nullptr;
  float pcx[3], pcy[3], pdx[3], pdy[3];
  if (tic < nb * N_C) {
    bl = tic >> 5;
    t = (c0 + bl) * N_C + (tic & 31);
    if (HM) {
      brow = nhm + (size_t)t * HW_C;
    } else {
      float cx = clampf(boxes[t * 4 + 0], -10.f, 10.f);
      float cy = clampf(boxes[t * 4 + 1], -10.f, 10.f);
      float w  = clampf(boxes[t * 4 + 2], -10.f, 10.f);
      float hh = clampf(boxes[t * 4 + 3], -10.f, 10.f);
      pcx[0] = cx; pcy[0] = cy;
      pdx[0] = w * w * 0.5f + 1e-6f; pdy[0] = hh * hh * 0.5f + 1e-6f;
      nG = 1;
    }
  } else {
    int ei = tic - nb * N_C;
    bl = ei >> 6;
    int e = (c0 + bl) * E_C + (ei & 63);
    t = TN_C + e;
    if (HM) {
      brow = ehm + (size_t)e * HW_C;
    } else {
      int sg = clampi(el[e], 0, N_C - 1) + (c0 + bl) * N_C;
      int dg = clampi(el[TE_C + e], 0, N_C - 1) + (c0 + bl) * N_C;
      float c1x = clampf(boxes[sg * 4 + 0], -10.f, 10.f);
      float c1y = clampf(boxes[sg * 4 + 1], -10.f, 10.f);
      float w1  = clampf(boxes[sg * 4 + 2], -10.f, 10.f);
      float h1  = clampf(boxes[sg * 4 + 3], -10.f, 10.f);
      float c2x = clampf(boxes[dg * 4 + 0], -10.f, 10.f);
      float c2y = clampf(boxes[dg * 4 + 1], -10.f, 10.f);
      float w2  = clampf(boxes[dg * 4 + 2], -10.f, 10.f);
      float h2  = clampf(boxes[dg * 4 + 3], -10.f, 10.f);
      pcx[0] = c1x; pcy[0] = c1y;
      pdx[0] = w1 * w1 * 0.5f + 1e-6f; pdy[0] = h1 * h1 * 0.5f + 1e-6f;
      pcx[1] = c2x; pcy[1] = c2y;
      pdx[1] = w2 * w2 * 0.5f + 1e-6f; pdy[1] = h2 * h2 * 0.5f + 1e-6f;
      float ux1 = fminf(c1x - w1 * 0.5f, c2x - w2 * 0.5f);
      float uy1 = fminf(c1y - h1 * 0.5f, c2y - h2 * 0.5f);
      float ux2 = fmaxf(c1x + w1 * 0.5f, c2x + w2 * 0.5f);
      float uy2 = fmaxf(c1y + h1 * 0.5f, c2y + h2 * 0.5f);
      float uw = ux2 - ux1, uh = uy2 - uy1;
      pcx[2] = 0.5f * (ux1 + ux2); pcy[2] = 0.5f * (uy1 + uy2);
      pdx[2] = uw * uw * 0.5f + 1e-6f; pdy[2] = uh * uh * 0.5f + 1e-6f;
      nG = 3;
    }
  }

  float qv[32];
  const float* qp = Qp + (size_t)t * D_C + h * DH_C;
#pragma unroll
  for (int d = 0; d < 32; d++) qv[d] = qp[d];

  const float scale = 0.17677669529663687f;
  const bf16* kvb = KV + (size_t)bl * HW_C * 512 + h * DH_C;

  float sarr[25];
  float m = -1e30f;
#pragma unroll
  for (int i = 0; i < 25; i++) {
    int kk = lane + i * 64;
    float kf[32];
    load_bf16x32(kvb + (size_t)kk * 512, kf);
    float s = 0.f;
#pragma unroll
    for (int d = 0; d < 32; d++) s = fmaf(kf[d], qv[d], s);
    float bias;
    if (HM) {
      bias = bf2f(brow[kk]);
    } else {
      int yy = kk / 40, xx = kk - yy * 40;
      float gx = ((float)xx + 0.5f) * 0.025f;
      float gy = ((float)yy + 0.5f) * 0.025f;
      bias = 0.f;
      for (int g = 0; g < nG; g++) {
        float dxv = gx - pcx[g], dyv = gy - pcy[g];
        float e = expf(-dxv * dxv / pdx[g]) * expf(-dyv * dyv / pdy[g]);
        bias = fmaxf(bias, e);
      }
    }
    s = clampf(s * scale + bias, -1e30f, 1e30f);
    sarr[i] = s;
    m = fmaxf(m, s);
  }
#pragma unroll
  for (int o = 1; o < 64; o <<= 1) m = fmaxf(m, __shfl_xor(m, o));

  float l = 0.f;
  float acc[32] = {};
#pragma unroll
  for (int i = 0; i < 25; i++) {
    int kk = lane + i * 64;
    float vf[32];
    load_bf16x32(kvb + (size_t)kk * 512 + 256, vf);
    float e = expf(fminf(sarr[i] - m, 0.f));
    l += e;
#pragma unroll
    for (int d = 0; d < 32; d++) acc[d] = fmaf(e, vf[d], acc[d]);
  }
#pragma unroll
  for (int o = 1; o < 64; o <<= 1) {
    l += __shfl_xor(l, o);
#pragma unroll
    for (int d = 0; d < 32; d++) acc[d] += __shfl_xor(acc[d], o);
  }
  if (lane == 0) {
    float inv = 1.0f / fmaxf(l, 1e-30f);
    float* op = O + (size_t)t * D_C + h * DH_C;
#pragma unroll
    for (int d = 0; d < 32; d++) op[d] = acc[d] * inv;
  }
}

// ---------------- GAT kernels ----------------

__global__ __launch_bounds__(256) void gat_logits_kernel(const float* __restrict__ hee,
                                                         const int* __restrict__ el,
                                                         const float* __restrict__ as,
                                                         const float* __restrict__ ad,
                                                         const float* __restrict__ ae,
                                                         float* __restrict__ logits) {
  int idx = blockIdx.x * 256 + threadIdx.x;
  int e = idx >> 3, h = idx & 7;
  int b = e >> 6;
  int sg = clampi(el[e], 0, N_C - 1) + b * N_C;
  int dg = clampi(el[TE_C + e], 0, N_C - 1) + b * N_C;
  const float* hs = hee + (size_t)sg * D_C + h * DH_C;
  const float* hd = hee + (size_t)dg * D_C + h * DH_C;
  const float* ep = hee + (size_t)(TN_C + e) * D_C + h * DH_C;
  float s = 0.f;
#pragma unroll
  for (int d = 0; d < 32; d++) {
    s += hs[d] * as[h * 32 + d] + hd[d] * ad[h * 32 + d] + ep[d] * ae[h * 32 + d];
  }
  s = clampf(s, -1e30f, 1e30f);
  logits[idx] = (s > 0.f) ? s : 0.2f * s;
}

__global__ __launch_bounds__(256) void gat_mden_kernel(const float* __restrict__ logits,
                                                       const int* __restrict__ el,
                                                       float* __restrict__ mb,
                                                       float* __restrict__ db) {
  int idx = blockIdx.x * 256 + threadIdx.x;
  int n = idx >> 3, h = idx & 7;
  int b = n >> 5;
  int e0 = b * E_C;
  float m = -1e30f;
  for (int k = 0; k < 64; k++) {
    int dg = clampi(el[TE_C + e0 + k], 0, N_C - 1) + b * N_C;
    if (dg == n) m = fmaxf(m, logits[(e0 + k) * 8 + h]);
  }
  float den = 0.f;
  for (int k = 0; k < 64; k++) {
    int dg = clampi(el[TE_C + e0 + k], 0, N_C - 1) + b * N_C;
    if (dg == n) den += expf(fminf(logits[(e0 + k) * 8 + h] - m, 0.f));
  }
  mb[idx] = m;
  db[idx] = den;
}

__global__ __launch_bounds__(256) void gat_alpha_kernel(const float* __restrict__ logits,
                                                        const int* __restrict__ el,
                                                        const float* __restrict__ mb,
                                                        const float* __restrict__ db,
                                                        float* __restrict__ al) {
  int idx = blockIdx.x * 256 + threadIdx.x;
  int e = idx >> 3, h = idx & 7;
  int b = e >> 6;
  int dg = clampi(el[TE_C + e], 0, N_C - 1) + b * N_C;
  float ex = expf(fminf(logits[idx] - mb[dg * 8 + h], 0.f));
  al[idx] = ex / (db[dg * 8 + h] + 1e-9f);
}

__global__ __launch_bounds__(256) void gat_nout_kernel(const float* __restrict__ hee,
                                                       const int* __restrict__ el,
                                                       const float* __restrict__ al,
                                                       float* __restrict__ noutp) {
  int n = blockIdx.x, d = threadIdx.x;
  int h = d >> 5;
  int b = n >> 5;
  int e0 = b * E_C;
  float acc = 0.f;
  for (int k = 0; k < 64; k++) {
    int e = e0 + k;
    int dg = clampi(el[TE_C + e], 0, N_C - 1) + b * N_C;
    if (dg == n) {
      int sg = clampi(el[e], 0, N_C - 1) + b * N_C;
      acc += al[e * 8 + h] * (hee[(size_t)sg * D_C + d] + hee[(size_t)(TN_C + e) * D_C + d]);
    }
  }
  noutp[(size_t)n * D_C + d] = acc;
}

// ---------------- residual + store ----------------

__global__ __launch_bounds__(256) void axpy_store_kernel(float* __restrict__ q,
                                                         const float* __restrict__ delta,
                                                         const float* __restrict__ ls,
                                                         float* __restrict__ out) {
  int idx = blockIdx.x * 256 + threadIdx.x;
  float v = q[idx] + ls[idx & 255] * delta[idx];
  q[idx] = v;
  out[idx] = v;
}

__global__ __launch_bounds__(256) void sanitize_kernel(float* __restrict__ out) {
  int idx = blockIdx.x * 256 + threadIdx.x;
  float v = out[idx];
  if (!(fabsf(v) <= 1e4f)) out[idx] = 0.f;
}

// ---------------- host ----------------

extern "C" void kernel_launch(void* const* d_in, const int* in_sizes, int n_in,
                              void* d_out, int out_size, void* d_ws, size_t ws_size,
                              hipStream_t stream) {
  const float* features   = (const float*)d_in[0];
  const float* boxes      = (const float*)d_in[1];
  const int*   edge_local = (const int*)d_in[2];
  const float* nodes0     = (const float*)d_in[3];
  const float* edges0     = (const float*)d_in[4];
  const float* ln1_g      = (const float*)d_in[5];
  const float* ln1_b      = (const float*)d_in[6];
  const float* attn_in_w  = (const float*)d_in[7];
  const float* attn_in_b  = (const float*)d_in[8];
  const float* attn_out_w = (const float*)d_in[9];
  const float* attn_out_b = (const float*)d_in[10];
  const float* ls1        = (const float*)d_in[11];
  const float* ln2_g      = (const float*)d_in[12];
  const float* ln2_b      = (const float*)d_in[13];
  const float* gat_wn     = (const float*)d_in[14];
  const float* gat_we     = (const float*)d_in[15];
  const float* gat_a_src  = (const float*)d_in[16];
  const float* gat_a_dst  = (const float*)d_in[17];
  const float* gat_a_edge = (const float*)d_in[18];
  const float* gat_wo     = (const float*)d_in[19];
  const float* gat_bo     = (const float*)d_in[20];
  const float* gat_woe    = (const float*)d_in[21];
  const float* gat_boe    = (const float*)d_in[22];
  const float* ls2        = (const float*)d_in[23];
  const float* ln3_g      = (const float*)d_in[24];
  const float* ln3_b      = (const float*)d_in[25];
  const float* ffn_w1     = (const float*)d_in[26];
  const float* ffn_b1     = (const float*)d_in[27];
  const float* ffn_w2     = (const float*)d_in[28];
  const float* ffn_b2     = (const float*)d_in[29];
  const float* ls3        = (const float*)d_in[30];
  float* out = (float*)d_out;

  size_t off = 0;
  auto alloc = [&](size_t bytes) -> void* {
    void* p = (char*)d_ws + off;
    off += (bytes + 255) & ~(size_t)255;
    return p;
  };
  const size_t TD = (size_t)TT_C * D_C;
  bf16*  emb   = (bf16*)alloc(TD * 2);
  float* q     = (float*)alloc(TD * 4);
  float* t0    = (float*)alloc(TD * 4);
  float* t1    = (float*)alloc(TD * 4);
  float* ybig  = (float*)alloc((size_t)TT_C * 512 * 4);
  float* logits= (float*)alloc((size_t)TE_C * 8 * 4);
  float* mb    = (float*)alloc((size_t)TN_C * 8 * 4);
  float* db    = (float*)alloc((size_t)TN_C * 8 * 4);
  float* al    = (float*)alloc((size_t)TE_C * 8 * 4);
  float* hee   = ybig;
  float* noutp = ybig + (size_t)TT_C * 256;

  const size_t KV_FULL = (size_t)B_C * HW_C * 512 * 2;     // 52.43 MB
  const size_t KV_CHNK = (size_t)4 * HW_C * 512 * 2;       // 6.55 MB
  const size_t HM_SZ   = (size_t)(TN_C + TE_C) * HW_C * 2; // 9.83 MB
  int mode;
  if (ws_size >= off + KV_FULL + HM_SZ + (1 << 20)) mode = 2;
  else if (ws_size >= off + KV_CHNK + HM_SZ + (1 << 20)) mode = 1;
  else mode = 0;
  bf16* KV = (bf16*)alloc(mode == 2 ? KV_FULL : KV_CHNK);
  bf16 *nhm = nullptr, *ehm = nullptr;
  if (mode >= 1) {
    nhm = (bf16*)alloc((size_t)TN_C * HW_C * 2);
    ehm = (bf16*)alloc((size_t)TE_C * HW_C * 2);
  }
  (void)in_sizes; (void)n_in; (void)out_size;

  embq_kernel<<<TT_C, 256, 0, stream>>>(boxes, edge_local, emb);
  initq_kernel<<<TT_C, 256, 0, stream>>>(nodes0, edges0, q);
  if (mode >= 1) {
    nodehm_kernel<<<TN_C, 256, 0, stream>>>(boxes, nhm);
    edgehm_kernel<<<TE_C, 256, 0, stream>>>(boxes, edge_local, nhm, ehm);
  }

  for (int l = 0; l < L_C; l++) {
    const float* Wq  = attn_in_w + (size_t)l * 768 * 256;
    const float* WKV = Wq + (size_t)256 * 256;
    const float* bq  = attn_in_b + (size_t)l * 768;
    const float* bKV = bq + 256;

    // LN1: q -> t0
    ln_kernel<<<TT_C, 256, 0, stream>>>(q, nullptr, nullptr, nullptr,
                                        ln1_g + l * 256, ln1_b + l * 256,
                                        t0, nullptr, nullptr);
    // Q projection: t0 @ Wq^T + bq -> t1
    mg<true, 1, float>(t0, 256, Wq, 256, bq, t1, 256, TT_C, 256, 256, stream);
    // K/V projection + attention (o -> t0)
    if (mode == 2) {
      mg<true, 1, bf16>(features, 256, WKV, 256, bKV, KV, 512,
                        B_C * HW_C, 512, 256, stream);
      fattn_kernel<<<B_C * NH_C, 192, 0, stream>>>(t1, KV, nhm, ehm, t0);
    } else {
      for (int c = 0; c < B_C / 4; c++) {
        mg<true, 1, bf16>(features + (size_t)c * 4 * HW_C * 256, 256,
                          WKV, 256, bKV, KV, 512, 4 * HW_C, 512, 256, stream);
        if (mode == 1)
          attn_kernel<true><<<4 * 192, 256, 0, stream>>>(
              t1, KV, nhm, ehm, boxes, edge_local, c * 4, 4, t0);
        else
          attn_kernel<false><<<4 * 192, 256, 0, stream>>>(
              t1, KV, nhm, ehm, boxes, edge_local, c * 4, 4, t0);
      }
    }
    // output projection: t0 @ Wo^T + bo -> t1
    mg<true, 1, float>(t0, 256, attn_out_w + (size_t)l * 65536, 256,
                       attn_out_b + l * 256, t1, 256, TT_C, 256, 256, stream);
    // LN2 (fused q += ls1*t1): -> q, x2=t0, xe=t1
    ln_kernel<<<TT_C, 256, 0, stream>>>(q, t1, ls1 + l * 256, q,
                                        ln2_g + l * 256, ln2_b + l * 256,
                                        t0, emb, t1);
    // GAT projections -> hee
    mg<false, 0, float>(t1, 256, gat_wn + (size_t)l * 65536, 256,
                        nullptr, hee, 256, TN_C, 256, 256, stream);
    mg<false, 0, float>(t1 + (size_t)TN_C * 256, 256,
                        gat_we + (size_t)l * 65536, 256, nullptr,
                        hee + (size_t)TN_C * 256, 256, TE_C, 256, 256, stream);
    gat_logits_kernel<<<(TE_C * 8) / 256, 256, 0, stream>>>(
        hee, edge_local, gat_a_src + l * 256, gat_a_dst + l * 256,
        gat_a_edge + l * 256, logits);
    gat_mden_kernel<<<(TN_C * 8) / 256, 256, 0, stream>>>(logits, edge_local, mb, db);
    gat_alpha_kernel<<<(TE_C * 8) / 256, 256, 0, stream>>>(logits, edge_local, mb, db, al);
    gat_nout_kernel<<<TN_C, 256, 0, stream>>>(hee, edge_local, al, noutp);
    // GAT output projections -> t1
    mg<false, 1, float>(noutp, 256, gat_wo + (size_t)l * 65536, 256,
                        gat_bo + l * 256, t1, 256, TN_C, 256, 256, stream);
    mg<false, 1, float>(hee + (size_t)TN_C * 256, 256,
                        gat_woe + (size_t)l * 65536, 256,
                        gat_boe + l * 256, t1 + (size_t)TN_C * 256, 256,
                        TE_C, 256, 256, stream);
    // LN3 (fused q = x2 + ls2*t1): base=t0 -> q, t0
    ln_kernel<<<TT_C, 256, 0, stream>>>(t0, t1, ls2 + l * 256, q,
                                        ln3_g + l * 256, ln3_b + l * 256,
                                        t0, nullptr, nullptr);
    // FFN in two 512-wide halves through ybig
    const float* W1 = ffn_w1 + (size_t)l * 262144;
    const float* W2 = ffn_w2 + (size_t)l * 262144;
    mg<false, 2, float>(t0, 256, W1, 1024, ffn_b1 + l * 1024,
                        ybig, 512, TT_C, 512, 256, stream);
    mg<false, 1, float>(ybig, 512, W2, 256, ffn_b2 + l * 256,
                        t1, 256, TT_C, 256, 512, stream);
    mg<false, 2, float>(t0, 256, W1 + 512, 1024, ffn_b1 + l * 1024 + 512,
                        ybig, 512, TT_C, 512, 256, stream);
    mg<false, 3, float>(ybig, 512, W2 + (size_t)512 * 256, 256,
                        nullptr, t1, 256, TT_C, 256, 512, stream);
    // q += ls3 * t1 ; store layer output
    axpy_store_kernel<<<TT_C, 256, 0, stream>>>(q, t1, ls3 + l * 256,
                                                out + (size_t)l * TD);
  }
  sanitize_kernel<<<(L_C * (int)TD) / 256, 256, 0, stream>>>(out);
}

// Round 7
// 1614.288 us; speedup vs baseline: 5.6734x; 1.3313x over previous
//
#include <hip/hip_runtime.h>
#include <hip/hip_bf16.h>
#include <math.h>

typedef __hip_bfloat16 bf16;
typedef unsigned short ushort_t;
typedef __attribute__((ext_vector_type(8))) short bf16x8;
typedef __attribute__((ext_vector_type(4))) float f32x4;

static constexpr int B_C   = 32;
static constexpr int N_C   = 32;
static constexpr int E_C   = 64;
static constexpr int HW_C  = 1600;
static constexpr int D_C   = 256;
static constexpr int NH_C  = 8;
static constexpr int DH_C  = 32;
static constexpr int L_C   = 6;
static constexpr int TN_C  = 1024;
static constexpr int TE_C  = 2048;
static constexpr int TT_C  = 3072;

__device__ __forceinline__ float bf2f(bf16 v) { return __bfloat162float(v); }
__device__ __forceinline__ int clampi(int v, int lo, int hi) {
  return v < lo ? lo : (v > hi ? hi : v);
}
__device__ __forceinline__ float clampf(float v, float lo, float hi) {
  return fminf(fmaxf(v, lo), hi);
}
__device__ __forceinline__ ushort_t f2b(float x) {
  bf16 h = __float2bfloat16(x);
  return *reinterpret_cast<ushort_t*>(&h);
}

__device__ __forceinline__ void unpack_bf2(unsigned v, float& a, float& b) {
  union { unsigned u; float f; } ua, ub;
  ua.u = v << 16;
  ub.u = v & 0xffff0000u;
  a = ua.f; b = ub.f;
}

__device__ __forceinline__ void load_bf16x32(const bf16* p, float* out) {
  const uint4* p4 = reinterpret_cast<const uint4*>(p);
#pragma unroll
  for (int w = 0; w < 4; w++) {
    uint4 u = p4[w];
    unpack_bf2(u.x, out[w * 8 + 0], out[w * 8 + 1]);
    unpack_bf2(u.y, out[w * 8 + 2], out[w * 8 + 3]);
    unpack_bf2(u.z, out[w * 8 + 4], out[w * 8 + 5]);
    unpack_bf2(u.w, out[w * 8 + 6], out[w * 8 + 7]);
  }
}

// ============ MFMA bf16 GEMM ============
static constexpr int SA = 40;

__device__ __forceinline__ void stage8(const float* __restrict__ src,
                                       ushort_t* __restrict__ dst) {
  float4 f0 = *(const float4*)src;
  float4 f1 = *(const float4*)(src + 4);
  ushort_t t[8] = { f2b(f0.x), f2b(f0.y), f2b(f0.z), f2b(f0.w),
                    f2b(f1.x), f2b(f1.y), f2b(f1.z), f2b(f1.w) };
  *(uint4*)dst = *(const uint4*)t;
}

// AB: A is bf16 (else f32). BT: B is (N,K) -> A@B^T, else (K,N).
// EPI: 0 none, 1 +bias, 2 +bias+GELU, 3 accumulate into C
template <bool AB, bool BT, int EPI, typename TC>
__global__ __launch_bounds__(256) void mgemm_kernel(
    const void* __restrict__ Ap, int lda, const float* __restrict__ Bw, int ldb,
    const float* __restrict__ bias, TC* __restrict__ C, int ldc,
    int M, int N, int K)
{
  __shared__ ushort_t As[64 * SA];
  __shared__ ushort_t Bs[64 * SA];
  const int tid = threadIdx.x;
  const int row0 = blockIdx.x * 64, col0 = blockIdx.y * 64;
  const int wave = tid >> 6, lane = tid & 63;
  const int wm = (wave >> 1) * 32, wn = (wave & 1) * 32;
  const int lm = lane & 15, quad = lane >> 4;

  f32x4 acc[2][2] = {};
  const int am = tid >> 2, akk = (tid & 3) * 8;
  const int bn = tid & 63, bkb = (tid >> 6) * 8;

  for (int k0 = 0; k0 < K; k0 += 32) {
    if (AB) {
      const bf16* A = (const bf16*)Ap;
      *(uint4*)&As[am * SA + akk] =
          *(const uint4*)(A + (size_t)(row0 + am) * lda + k0 + akk);
    } else {
      stage8((const float*)Ap + (size_t)(row0 + am) * lda + k0 + akk,
             &As[am * SA + akk]);
    }
    if (BT) {
      stage8(Bw + (size_t)(col0 + am) * ldb + k0 + akk, &Bs[am * SA + akk]);
    } else {
      ushort_t t[8];
#pragma unroll
      for (int j = 0; j < 8; j++)
        t[j] = f2b(Bw[(size_t)(k0 + bkb + j) * ldb + col0 + bn]);
      *(uint4*)(&Bs[bn * SA + bkb]) = *(const uint4*)t;
    }
    __syncthreads();
    bf16x8 a0 = *(const bf16x8*)(&As[(wm + lm) * SA + quad * 8]);
    bf16x8 a1 = *(const bf16x8*)(&As[(wm + 16 + lm) * SA + quad * 8]);
    bf16x8 b0 = *(const bf16x8*)(&Bs[(wn + lm) * SA + quad * 8]);
    bf16x8 b1 = *(const bf16x8*)(&Bs[(wn + 16 + lm) * SA + quad * 8]);
    acc[0][0] = __builtin_amdgcn_mfma_f32_16x16x32_bf16(a0, b0, acc[0][0], 0, 0, 0);
    acc[0][1] = __builtin_amdgcn_mfma_f32_16x16x32_bf16(a0, b1, acc[0][1], 0, 0, 0);
    acc[1][0] = __builtin_amdgcn_mfma_f32_16x16x32_bf16(a1, b0, acc[1][0], 0, 0, 0);
    acc[1][1] = __builtin_amdgcn_mfma_f32_16x16x32_bf16(a1, b1, acc[1][1], 0, 0, 0);
    __syncthreads();
  }

#pragma unroll
  for (int ti = 0; ti < 2; ti++) {
#pragma unroll
    for (int tj = 0; tj < 2; tj++) {
      int gc = col0 + wn + tj * 16 + lm;
      float bsv = (EPI == 1 || EPI == 2) ? bias[gc] : 0.f;
#pragma unroll
      for (int r = 0; r < 4; r++) {
        int gr = row0 + wm + ti * 16 + quad * 4 + r;
        float v = acc[ti][tj][r];
        TC* cp = C + (size_t)gr * ldc + gc;
        if (EPI == 1 || EPI == 2) v += bsv;
        if (EPI == 2) v = 0.5f * v * (1.0f + erff(v * 0.70710678118654752f));
        if (EPI == 3) v += (float)(*cp);
        *cp = (TC)v;
      }
    }
  }
}

template <bool AB, bool BT, int EPI, typename TC>
static void mg(const void* A, int lda, const float* Bw, int ldb,
               const float* bias, void* C, int ldc,
               int M, int N, int K, hipStream_t s) {
  dim3 g(M / 64, N / 64);
  mgemm_kernel<AB, BT, EPI, TC><<<g, 256, 0, s>>>(A, lda, Bw, ldb, bias,
                                                  (TC*)C, ldc, M, N, K);
}

// Dual-source GEMM (BT=false): rows < M1 use (A1,B1,bias1), rest (A2,B2,bias2).
template <int EPI>
__global__ __launch_bounds__(256) void mgemm_dual_kernel(
    const float* __restrict__ A1, const float* __restrict__ A2, int M1, int lda,
    const float* __restrict__ B1, const float* __restrict__ B2, int ldb,
    const float* __restrict__ bias1, const float* __restrict__ bias2,
    float* __restrict__ C, int ldc, int K)
{
  __shared__ ushort_t As[64 * SA];
  __shared__ ushort_t Bs[64 * SA];
  const int tid = threadIdx.x;
  const int grow0 = blockIdx.x * 64, col0 = blockIdx.y * 64;
  const bool first = grow0 < M1;
  const float* A = first ? A1 : A2;
  const float* Bw = first ? B1 : B2;
  const float* bias = first ? bias1 : bias2;
  const int row0 = first ? grow0 : grow0 - M1;

  const int wave = tid >> 6, lane = tid & 63;
  const int wm = (wave >> 1) * 32, wn = (wave & 1) * 32;
  const int lm = lane & 15, quad = lane >> 4;

  f32x4 acc[2][2] = {};
  const int am = tid >> 2, akk = (tid & 3) * 8;
  const int bn = tid & 63, bkb = (tid >> 6) * 8;

  for (int k0 = 0; k0 < K; k0 += 32) {
    stage8(A + (size_t)(row0 + am) * lda + k0 + akk, &As[am * SA + akk]);
    ushort_t t[8];
#pragma unroll
    for (int j = 0; j < 8; j++)
      t[j] = f2b(Bw[(size_t)(k0 + bkb + j) * ldb + col0 + bn]);
    *(uint4*)(&Bs[bn * SA + bkb]) = *(const uint4*)t;
    __syncthreads();
    bf16x8 a0 = *(const bf16x8*)(&As[(wm + lm) * SA + quad * 8]);
    bf16x8 a1 = *(const bf16x8*)(&As[(wm + 16 + lm) * SA + quad * 8]);
    bf16x8 b0 = *(const bf16x8*)(&Bs[(wn + lm) * SA + quad * 8]);
    bf16x8 b1 = *(const bf16x8*)(&Bs[(wn + 16 + lm) * SA + quad * 8]);
    acc[0][0] = __builtin_amdgcn_mfma_f32_16x16x32_bf16(a0, b0, acc[0][0], 0, 0, 0);
    acc[0][1] = __builtin_amdgcn_mfma_f32_16x16x32_bf16(a0, b1, acc[0][1], 0, 0, 0);
    acc[1][0] = __builtin_amdgcn_mfma_f32_16x16x32_bf16(a1, b0, acc[1][0], 0, 0, 0);
    acc[1][1] = __builtin_amdgcn_mfma_f32_16x16x32_bf16(a1, b1, acc[1][1], 0, 0, 0);
    __syncthreads();
  }

#pragma unroll
  for (int ti = 0; ti < 2; ti++) {
#pragma unroll
    for (int tj = 0; tj < 2; tj++) {
      int gc = col0 + wn + tj * 16 + lm;
      float bsv = (EPI == 1) ? bias[gc] : 0.f;
#pragma unroll
      for (int r = 0; r < 4; r++) {
        int gr = grow0 + wm + ti * 16 + quad * 4 + r;
        float v = acc[ti][tj][r];
        if (EPI == 1) v += bsv;
        C[(size_t)gr * ldc + gc] = v;
      }
    }
  }
}

// ---------------- precompute kernels ----------------

__global__ __launch_bounds__(256) void featconv_kernel(const float* __restrict__ f,
                                                       bf16* __restrict__ fb) {
  int idx = (blockIdx.x * 256 + threadIdx.x) * 8;
  float4 a = *(const float4*)(f + idx);
  float4 b = *(const float4*)(f + idx + 4);
  ushort_t t[8] = { f2b(a.x), f2b(a.y), f2b(a.z), f2b(a.w),
                    f2b(b.x), f2b(b.y), f2b(b.z), f2b(b.w) };
  *(uint4*)(fb + idx) = *(const uint4*)t;
}

__global__ __launch_bounds__(256) void nodehm_kernel(const float* __restrict__ boxes,
                                                     bf16* __restrict__ hm) {
  int t = blockIdx.x;
  float cx = clampf(boxes[t * 4 + 0], -10.f, 10.f);
  float cy = clampf(boxes[t * 4 + 1], -10.f, 10.f);
  float w  = clampf(boxes[t * 4 + 2], -10.f, 10.f);
  float h  = clampf(boxes[t * 4 + 3], -10.f, 10.f);
  float dwx = w * w * 0.5f + 1e-6f;
  float dhy = h * h * 0.5f + 1e-6f;
  for (int pix = threadIdx.x; pix < HW_C; pix += 256) {
    int y = pix / 40, x = pix - y * 40;
    float gx = ((float)x + 0.5f) * 0.025f;
    float gy = ((float)y + 0.5f) * 0.025f;
    hm[(size_t)t * HW_C + pix] = __float2bfloat16(
        expf(-(gx - cx) * (gx - cx) / dwx) * expf(-(gy - cy) * (gy - cy) / dhy));
  }
}

__global__ __launch_bounds__(256) void edgehm_kernel(const float* __restrict__ boxes,
                                                     const int* __restrict__ el,
                                                     const bf16* __restrict__ nhm,
                                                     bf16* __restrict__ ehm) {
  int e = blockIdx.x;
  int b = e >> 6;
  int sg = clampi(el[e], 0, N_C - 1) + b * N_C;
  int dg = clampi(el[TE_C + e], 0, N_C - 1) + b * N_C;
  float c1x = clampf(boxes[sg * 4 + 0], -10.f, 10.f);
  float c1y = clampf(boxes[sg * 4 + 1], -10.f, 10.f);
  float w1  = clampf(boxes[sg * 4 + 2], -10.f, 10.f);
  float h1  = clampf(boxes[sg * 4 + 3], -10.f, 10.f);
  float c2x = clampf(boxes[dg * 4 + 0], -10.f, 10.f);
  float c2y = clampf(boxes[dg * 4 + 1], -10.f, 10.f);
  float w2  = clampf(boxes[dg * 4 + 2], -10.f, 10.f);
  float h2  = clampf(boxes[dg * 4 + 3], -10.f, 10.f);
  float ux1 = fminf(c1x - w1 * 0.5f, c2x - w2 * 0.5f);
  float uy1 = fminf(c1y - h1 * 0.5f, c2y - h2 * 0.5f);
  float ux2 = fmaxf(c1x + w1 * 0.5f, c2x + w2 * 0.5f);
  float uy2 = fmaxf(c1y + h1 * 0.5f, c2y + h2 * 0.5f);
  float cx = 0.5f * (ux1 + ux2), cy = 0.5f * (uy1 + uy2);
  float w = ux2 - ux1, h = uy2 - uy1;
  float dwx = w * w * 0.5f + 1e-6f;
  float dhy = h * h * 0.5f + 1e-6f;
  for (int pix = threadIdx.x; pix < HW_C; pix += 256) {
    int y = pix / 40, x = pix - y * 40;
    float gx = ((float)x + 0.5f) * 0.025f;
    float gy = ((float)y + 0.5f) * 0.025f;
    float u = expf(-(gx - cx) * (gx - cx) / dwx) * expf(-(gy - cy) * (gy - cy) / dhy);
    float v = fmaxf(fmaxf(bf2f(nhm[(size_t)sg * HW_C + pix]),
                          bf2f(nhm[(size_t)dg * HW_C + pix])), u);
    ehm[(size_t)e * HW_C + pix] = __float2bfloat16(v);
  }
}

__global__ __launch_bounds__(256) void embq_kernel(const float* __restrict__ boxes,
                                                   const int* __restrict__ el,
                                                   bf16* __restrict__ emb) {
  int t = blockIdx.x;
  int d = threadIdx.x;
  int c = d >> 6, inner = d & 63;
  float v;
  if (t < TN_C) {
    v = boxes[t * 4 + c];
  } else {
    int e = t - TN_C;
    int b = e >> 6;
    int sg = clampi(el[e], 0, N_C - 1) + b * N_C;
    int dg = clampi(el[TE_C + e], 0, N_C - 1) + b * N_C;
    v = boxes[sg * 4 + c] - boxes[dg * 4 + c];
  }
  v = clampf(v, -100.f, 100.f);
  int i = inner & 31;
  float freq = expf(-9.210340371976184f * (float)i / 32.0f);
  float ang = v * freq;
  emb[(size_t)t * D_C + d] = __float2bfloat16((inner < 32) ? sinf(ang) : cosf(ang));
}

__global__ __launch_bounds__(256) void initq_kernel(const float* __restrict__ nodes0,
                                                    const float* __restrict__ edges0,
                                                    float* __restrict__ q) {
  int idx = blockIdx.x * 256 + threadIdx.x;
  int t = idx >> 8;
  q[idx] = (t < TN_C) ? nodes0[idx] : edges0[idx - TN_C * D_C];
}

// -------- LayerNorm with optional fused residual/xe ----------

__global__ __launch_bounds__(256) void ln_kernel(const float* __restrict__ base,
                                                 const float* __restrict__ delta,
                                                 const float* __restrict__ ls,
                                                 float* __restrict__ qsave,
                                                 const float* __restrict__ g,
                                                 const float* __restrict__ bb,
                                                 float* __restrict__ xout,
                                                 const bf16* __restrict__ emb,
                                                 float* __restrict__ xeout) {
  __shared__ float red[4];
  int r = blockIdx.x, tid = threadIdx.x;
  size_t bofs = (size_t)r * D_C;
  float v = base[bofs + tid];
  if (delta) v += ls[tid] * delta[bofs + tid];
  if (qsave) qsave[bofs + tid] = v;
  float s = v;
#pragma unroll
  for (int o = 1; o < 64; o <<= 1) s += __shfl_xor(s, o);
  if ((tid & 63) == 0) red[tid >> 6] = s;
  __syncthreads();
  float mean = (red[0] + red[1] + red[2] + red[3]) * (1.0f / 256.0f);
  __syncthreads();
  float d = v - mean;
  float s2 = d * d;
#pragma unroll
  for (int o = 1; o < 64; o <<= 1) s2 += __shfl_xor(s2, o);
  if ((tid & 63) == 0) red[tid >> 6] = s2;
  __syncthreads();
  float var = (red[0] + red[1] + red[2] + red[3]) * (1.0f / 256.0f);
  float xo = d * rsqrtf(var + 1e-5f) * g[tid] + bb[tid];
  xout[bofs + tid] = xo;
  if (xeout) xeout[bofs + tid] = xo + bf2f(emb[bofs + tid]);
}

// ============ flash MFMA attention, split-K ============
// grid = SPL*256; blockIdx = s*256 + h*32 + b (all wgs of batch b on XCD b%8).
// Each wg: 96 query rows (3 waves x 32), keys [s*800, s*800+800), 160/chunk.
// Outputs unnormalized Opart + per-row m,l; merged by fmerge_kernel.
static constexpr int ATK = 160;
static constexpr int KSTR = 40;    // Kl [key][dim] stride (shorts)
static constexpr int VSTR = 168;   // Vt [dim][key] stride (shorts)
static constexpr int PSTR = 168;   // Pl [row][key] stride (shorts)
static constexpr int SPL = 2;
static constexpr int KEYS_PER = HW_C / SPL;  // 800

__global__ __launch_bounds__(192) void fattn_kernel(const float* __restrict__ Qp,
                                                    const bf16* __restrict__ KV,
                                                    const bf16* __restrict__ nhm,
                                                    const bf16* __restrict__ ehm,
                                                    float* __restrict__ Opart,
                                                    float* __restrict__ mpart,
                                                    float* __restrict__ lpart) {
  __shared__ ushort_t Kl[ATK * KSTR];
  __shared__ ushort_t Vt[32 * VSTR];
  __shared__ ushort_t Pl[3 * 32 * PSTR];

  const int s = blockIdx.x >> 8;
  const int rem = blockIdx.x & 255;
  const int h = rem >> 5, b = rem & 31;
  const int tid = threadIdx.x;
  const int wave = tid >> 6, lane = tid & 63;
  const int lm = lane & 15, quad = lane >> 4;
  const int wr0 = wave * 32;

  int tok[2][4];
  const bf16* brow[2][4];
#pragma unroll
  for (int mt = 0; mt < 2; mt++)
#pragma unroll
    for (int r = 0; r < 4; r++) {
      int row = wr0 + mt * 16 + quad * 4 + r;
      if (row < 32) {
        int t = b * N_C + row;
        tok[mt][r] = t; brow[mt][r] = nhm + (size_t)t * HW_C;
      } else {
        int e = b * E_C + (row - 32);
        tok[mt][r] = TN_C + e; brow[mt][r] = ehm + (size_t)e * HW_C;
      }
    }

  bf16x8 qa[2];
#pragma unroll
  for (int mt = 0; mt < 2; mt++) {
    int row = wr0 + mt * 16 + lm;
    int t = (row < 32) ? (b * N_C + row) : (TN_C + b * E_C + (row - 32));
    const float* qp = Qp + (size_t)t * D_C + h * DH_C + quad * 8;
    ushort_t tmp[8];
#pragma unroll
    for (int j = 0; j < 8; j++) tmp[j] = f2b(qp[j]);
    qa[mt] = *(const bf16x8*)tmp;
  }

  f32x4 Oacc[2][2] = {};
  float mrow[2][4], lrow[2][4];
#pragma unroll
  for (int mt = 0; mt < 2; mt++)
#pragma unroll
    for (int r = 0; r < 4; r++) { mrow[mt][r] = -1e30f; lrow[mt][r] = 0.f; }

  const bf16* kvb = KV + (size_t)b * HW_C * 512 + h * DH_C;
  const float scale = 0.17677669529663687f;
  ushort_t* Pw = &Pl[wave * 32 * PSTR];

  const int kend = s * KEYS_PER + KEYS_PER;
  for (int k0 = s * KEYS_PER; k0 < kend; k0 += ATK) {
    // stage K [key][dim] (16B) and V transposed [dim][key]
    for (int slot = tid; slot < ATK * 4; slot += 192) {
      int key = slot >> 2, dc = (slot & 3) * 8;
      const bf16* src = kvb + (size_t)(k0 + key) * 512 + dc;
      *(uint4*)&Kl[key * KSTR + dc] = *(const uint4*)src;
      uint4 v4 = *(const uint4*)(src + 256);
      ushort_t vs[8]; *(uint4*)vs = v4;
#pragma unroll
      for (int j = 0; j < 8; j++) Vt[(dc + j) * VSTR + key] = vs[j];
    }
    __syncthreads();

    float sv[2][10][4];
#pragma unroll
    for (int nt = 0; nt < 10; nt++) {
      bf16x8 kb = *(const bf16x8*)&Kl[(nt * 16 + lm) * KSTR + quad * 8];
#pragma unroll
      for (int mt = 0; mt < 2; mt++) {
        f32x4 d = {};
        d = __builtin_amdgcn_mfma_f32_16x16x32_bf16(qa[mt], kb, d, 0, 0, 0);
#pragma unroll
        for (int r = 0; r < 4; r++) sv[mt][nt][r] = d[r];
      }
    }

#pragma unroll
    for (int mt = 0; mt < 2; mt++)
#pragma unroll
      for (int r = 0; r < 4; r++) {
        const bf16* br = brow[mt][r] + k0 + lm;
        float mx = -1e30f;
#pragma unroll
        for (int nt = 0; nt < 10; nt++) {
          float v = sv[mt][nt][r] * scale + bf2f(br[nt * 16]);
          sv[mt][nt][r] = v;
          mx = fmaxf(mx, v);
        }
#pragma unroll
        for (int o = 1; o < 16; o <<= 1) mx = fmaxf(mx, __shfl_xor(mx, o));
        float mn = fmaxf(mrow[mt][r], mx);
        float lsum = 0.f;
        int prow = (mt * 16 + quad * 4 + r) * PSTR;
#pragma unroll
        for (int nt = 0; nt < 10; nt++) {
          float p = expf(fminf(sv[mt][nt][r] - mn, 0.f));
          lsum += p;
          Pw[prow + nt * 16 + lm] = f2b(p);
        }
#pragma unroll
        for (int o = 1; o < 16; o <<= 1) lsum += __shfl_xor(lsum, o);
        float alpha = expf(fminf(mrow[mt][r] - mn, 0.f));
        lrow[mt][r] = lrow[mt][r] * alpha + lsum;
        mrow[mt][r] = mn;
        Oacc[mt][0][r] *= alpha;
        Oacc[mt][1][r] *= alpha;
      }

#pragma unroll
    for (int kc = 0; kc < 5; kc++) {
#pragma unroll
      for (int nt = 0; nt < 2; nt++) {
        bf16x8 vfrag = *(const bf16x8*)&Vt[(nt * 16 + lm) * VSTR + kc * 32 + quad * 8];
#pragma unroll
        for (int mt = 0; mt < 2; mt++) {
          bf16x8 pa = *(const bf16x8*)&Pw[(mt * 16 + lm) * PSTR + kc * 32 + quad * 8];
          Oacc[mt][nt] = __builtin_amdgcn_mfma_f32_16x16x32_bf16(pa, vfrag,
                                                                 Oacc[mt][nt], 0, 0, 0);
        }
      }
    }
    __syncthreads();
  }

  const size_t TD = (size_t)TT_C * D_C;
#pragma unroll
  for (int mt = 0; mt < 2; mt++)
#pragma unroll
    for (int r = 0; r < 4; r++) {
      float* op = Opart + (size_t)s * TD + (size_t)tok[mt][r] * D_C + h * DH_C;
      op[lm]      = Oacc[mt][0][r];
      op[16 + lm] = Oacc[mt][1][r];
      if (lm == 0) {
        int mi = s * TT_C * NH_C + tok[mt][r] * NH_C + h;
        mpart[mi] = mrow[mt][r];
        lpart[mi] = lrow[mt][r];
      }
    }
}

__global__ __launch_bounds__(256) void fmerge_kernel(const float* __restrict__ Opart,
                                                     const float* __restrict__ mpart,
                                                     const float* __restrict__ lpart,
                                                     float* __restrict__ O) {
  int idx = blockIdx.x * 256 + threadIdx.x;
  int t = idx >> 8, d = idx & 255, h = d >> 5;
  const size_t TD = (size_t)TT_C * D_C;
  int mi = t * NH_C + h;
  float m0 = mpart[mi], m1 = mpart[TT_C * NH_C + mi];
  float l0 = lpart[mi], l1 = lpart[TT_C * NH_C + mi];
  float mm = fmaxf(m0, m1);
  float a0 = expf(fminf(m0 - mm, 0.f)), a1 = expf(fminf(m1 - mm, 0.f));
  float l = l0 * a0 + l1 * a1;
  O[idx] = (Opart[idx] * a0 + Opart[TD + idx] * a1) / fmaxf(l, 1e-30f);
}

// ------- legacy wave-per-(token,head) attention (small-ws fallback) -------

template <bool HM>
__global__ __launch_bounds__(256) void attn_kernel(const float* __restrict__ Qp,
                                                   const bf16* __restrict__ KV,
                                                   const bf16* __restrict__ nhm,
                                                   const bf16* __restrict__ ehm,
                                                   const float* __restrict__ boxes,
                                                   const int* __restrict__ el,
                                                   int c0, int nb,
                                                   float* __restrict__ O) {
  int wid = threadIdx.x >> 6;
  int lane = threadIdx.x & 63;
  int gw = blockIdx.x * 4 + wid;
  int tic = gw >> 3, h = gw & 7;
  int t, bl, nG = 0;
  const bf16* brow = nullptr;
  float pcx[3], pcy[3], pdx[3], pdy[3];
  if (tic < nb * N_C) {
    bl = tic >> 5;
    t = (c0 + bl) * N_C + (tic & 31);
    if (HM) {
      brow = nhm + (size_t)t * HW_C;
    } else {
      float cx = clampf(boxes[t * 4 + 0], -10.f, 10.f);
      float cy = clampf(boxes[t * 4 + 1], -10.f, 10.f);
      float w  = clampf(boxes[t * 4 + 2], -10.f, 10.f);
      float hh = clampf(boxes[t * 4 + 3], -10.f, 10.f);
      pcx[0] = cx; pcy[0] = cy;
      pdx[0] = w * w * 0.5f + 1e-6f; pdy[0] = hh * hh * 0.5f + 1e-6f;
      nG = 1;
    }
  } else {
    int ei = tic - nb * N_C;
    bl = ei >> 6;
    int e = (c0 + bl) * E_C + (ei & 63);
    t = TN_C + e;
    if (HM) {
      brow = ehm + (size_t)e * HW_C;
    } else {
      int sg = clampi(el[e], 0, N_C - 1) + (c0 + bl) * N_C;
      int dg = clampi(el[TE_C + e], 0, N_C - 1) + (c0 + bl) * N_C;
      float c1x = clampf(boxes[sg * 4 + 0], -10.f, 10.f);
      float c1y = clampf(boxes[sg * 4 + 1], -10.f, 10.f);
      float w1  = clampf(boxes[sg * 4 + 2], -10.f, 10.f);
      float h1  = clampf(boxes[sg * 4 + 3], -10.f, 10.f);
      float c2x = clampf(boxes[dg * 4 + 0], -10.f, 10.f);
      float c2y = clampf(boxes[dg * 4 + 1], -10.f, 10.f);
      float w2  = clampf(boxes[dg * 4 + 2], -10.f, 10.f);
      float h2  = clampf(boxes[dg * 4 + 3], -10.f, 10.f);
      pcx[0] = c1x; pcy[0] = c1y;
      pdx[0] = w1 * w1 * 0.5f + 1e-6f; pdy[0] = h1 * h1 * 0.5f + 1e-6f;
      pcx[1] = c2x; pcy[1] = c2y;
      pdx[1] = w2 * w2 * 0.5f + 1e-6f; pdy[1] = h2 * h2 * 0.5f + 1e-6f;
      float ux1 = fminf(c1x - w1 * 0.5f, c2x - w2 * 0.5f);
      float uy1 = fminf(c1y - h1 * 0.5f, c2y - h2 * 0.5f);
      float ux2 = fmaxf(c1x + w1 * 0.5f, c2x + w2 * 0.5f);
      float uy2 = fmaxf(c1y + h1 * 0.5f, c2y + h2 * 0.5f);
      float uw = ux2 - ux1, uh = uy2 - uy1;
      pcx[2] = 0.5f * (ux1 + ux2); pcy[2] = 0.5f * (uy1 + uy2);
      pdx[2] = uw * uw * 0.5f + 1e-6f; pdy[2] = uh * uh * 0.5f + 1e-6f;
      nG = 3;
    }
  }

  float qv[32];
  const float* qp = Qp + (size_t)t * D_C + h * DH_C;
#pragma unroll
  for (int d = 0; d < 32; d++) qv[d] = qp[d];

  const float scale = 0.17677669529663687f;
  const bf16* kvb = KV + (size_t)bl * HW_C * 512 + h * DH_C;

  float sarr[25];
  float m = -1e30f;
#pragma unroll
  for (int i = 0; i < 25; i++) {
    int kk = lane + i * 64;
    float kf[32];
    load_bf16x32(kvb + (size_t)kk * 512, kf);
    float s = 0.f;
#pragma unroll
    for (int d = 0; d < 32; d++) s = fmaf(kf[d], qv[d], s);
    float bias;
    if (HM) {
      bias = bf2f(brow[kk]);
    } else {
      int yy = kk / 40, xx = kk - yy * 40;
      float gx = ((float)xx + 0.5f) * 0.025f;
      float gy = ((float)yy + 0.5f) * 0.025f;
      bias = 0.f;
      for (int g = 0; g < nG; g++) {
        float dxv = gx - pcx[g], dyv = gy - pcy[g];
        float e = expf(-dxv * dxv / pdx[g]) * expf(-dyv * dyv / pdy[g]);
        bias = fmaxf(bias, e);
      }
    }
    s = clampf(s * scale + bias, -1e30f, 1e30f);
    sarr[i] = s;
    m = fmaxf(m, s);
  }
#pragma unroll
  for (int o = 1; o < 64; o <<= 1) m = fmaxf(m, __shfl_xor(m, o));

  float l = 0.f;
  float acc[32] = {};
#pragma unroll
  for (int i = 0; i < 25; i++) {
    int kk = lane + i * 64;
    float vf[32];
    load_bf16x32(kvb + (size_t)kk * 512 + 256, vf);
    float e = expf(fminf(sarr[i] - m, 0.f));
    l += e;
#pragma unroll
    for (int d = 0; d < 32; d++) acc[d] = fmaf(e, vf[d], acc[d]);
  }
#pragma unroll
  for (int o = 1; o < 64; o <<= 1) {
    l += __shfl_xor(l, o);
#pragma unroll
    for (int d = 0; d < 32; d++) acc[d] += __shfl_xor(acc[d], o);
  }
  if (lane == 0) {
    float inv = 1.0f / fmaxf(l, 1e-30f);
    float* op = O + (size_t)t * D_C + h * DH_C;
#pragma unroll
    for (int d = 0; d < 32; d++) op[d] = acc[d] * inv;
  }
}

// ---------------- GAT kernels ----------------

// One block per batch: logits (512), m/den (256), alpha (512).
__global__ __launch_bounds__(512) void gat_fused_kernel(const float* __restrict__ hee,
                                                        const int* __restrict__ el,
                                                        const float* __restrict__ as,
                                                        const float* __restrict__ ad,
                                                        const float* __restrict__ ae,
                                                        float* __restrict__ al) {
  __shared__ float lg[512];
  __shared__ float ml[256], dl[256];
  int b = blockIdx.x, tid = threadIdx.x;
  int e_l = tid >> 3, h = tid & 7;
  int e = b * E_C + e_l;
  int sgl = clampi(el[e], 0, N_C - 1);
  int dgl = clampi(el[TE_C + e], 0, N_C - 1);
  {
    const float* hs = hee + (size_t)(b * N_C + sgl) * D_C + h * DH_C;
    const float* hd = hee + (size_t)(b * N_C + dgl) * D_C + h * DH_C;
    const float* ep = hee + (size_t)(TN_C + e) * D_C + h * DH_C;
    float s = 0.f;
#pragma unroll
    for (int d = 0; d < 32; d++)
      s += hs[d] * as[h * 32 + d] + hd[d] * ad[h * 32 + d] + ep[d] * ae[h * 32 + d];
    s = clampf(s, -1e30f, 1e30f);
    lg[tid] = (s > 0.f) ? s : 0.2f * s;
  }
  __syncthreads();
  if (tid < 256) {
    int n = tid >> 3, hh = tid & 7;
    float m = -1e30f;
    for (int k = 0; k < 64; k++) {
      int dg = clampi(el[TE_C + b * E_C + k], 0, N_C - 1);
      if (dg == n) m = fmaxf(m, lg[k * 8 + hh]);
    }
    float den = 0.f;
    for (int k = 0; k < 64; k++) {
      int dg = clampi(el[TE_C + b * E_C + k], 0, N_C - 1);
      if (dg == n) den += expf(fminf(lg[k * 8 + hh] - m, 0.f));
    }
    ml[tid] = m; dl[tid] = den;
  }
  __syncthreads();
  float ex = expf(fminf(lg[tid] - ml[dgl * 8 + h], 0.f));
  al[(size_t)e * 8 + h] = ex / (dl[dgl * 8 + h] + 1e-9f);
}

__global__ __launch_bounds__(256) void gat_nout_kernel(const float* __restrict__ hee,
                                                       const int* __restrict__ el,
                                                       const float* __restrict__ al,
                                                       float* __restrict__ noutp) {
  int n = blockIdx.x, d = threadIdx.x;
  int h = d >> 5;
  int b = n >> 5;
  int e0 = b * E_C;
  float acc = 0.f;
  for (int k = 0; k < 64; k++) {
    int e = e0 + k;
    int dg = clampi(el[TE_C + e], 0, N_C - 1) + b * N_C;
    if (dg == n) {
      int sg = clampi(el[e], 0, N_C - 1) + b * N_C;
      acc += al[e * 8 + h] * (hee[(size_t)sg * D_C + d] + hee[(size_t)(TN_C + e) * D_C + d]);
    }
  }
  noutp[(size_t)n * D_C + d] = acc;
}

// ---------------- residual + store (sanitized out) ----------------

__global__ __launch_bounds__(256) void axpy_store_kernel(float* __restrict__ q,
                                                         const float* __restrict__ delta,
                                                         const float* __restrict__ ls,
                                                         float* __restrict__ out) {
  int idx = blockIdx.x * 256 + threadIdx.x;
  float v = q[idx] + ls[idx & 255] * delta[idx];
  q[idx] = v;
  out[idx] = (fabsf(v) <= 1e4f) ? v : 0.f;
}

// ---------------- host ----------------

extern "C" void kernel_launch(void* const* d_in, const int* in_sizes, int n_in,
                              void* d_out, int out_size, void* d_ws, size_t ws_size,
                              hipStream_t stream) {
  const float* features   = (const float*)d_in[0];
  const float* boxes      = (const float*)d_in[1];
  const int*   edge_local = (const int*)d_in[2];
  const float* nodes0     = (const float*)d_in[3];
  const float* edges0     = (const float*)d_in[4];
  const float* ln1_g      = (const float*)d_in[5];
  const float* ln1_b      = (const float*)d_in[6];
  const float* attn_in_w  = (const float*)d_in[7];
  const float* attn_in_b  = (const float*)d_in[8];
  const float* attn_out_w = (const float*)d_in[9];
  const float* attn_out_b = (const float*)d_in[10];
  const float* ls1        = (const float*)d_in[11];
  const float* ln2_g      = (const float*)d_in[12];
  const float* ln2_b      = (const float*)d_in[13];
  const float* gat_wn     = (const float*)d_in[14];
  const float* gat_we     = (const float*)d_in[15];
  const float* gat_a_src  = (const float*)d_in[16];
  const float* gat_a_dst  = (const float*)d_in[17];
  const float* gat_a_edge = (const float*)d_in[18];
  const float* gat_wo     = (const float*)d_in[19];
  const float* gat_bo     = (const float*)d_in[20];
  const float* gat_woe    = (const float*)d_in[21];
  const float* gat_boe    = (const float*)d_in[22];
  const float* ls2        = (const float*)d_in[23];
  const float* ln3_g      = (const float*)d_in[24];
  const float* ln3_b      = (const float*)d_in[25];
  const float* ffn_w1     = (const float*)d_in[26];
  const float* ffn_b1     = (const float*)d_in[27];
  const float* ffn_w2     = (const float*)d_in[28];
  const float* ffn_b2     = (const float*)d_in[29];
  const float* ls3        = (const float*)d_in[30];
  float* out = (float*)d_out;

  size_t off = 0;
  auto alloc = [&](size_t bytes) -> void* {
    void* p = (char*)d_ws + off;
    off += (bytes + 255) & ~(size_t)255;
    return p;
  };
  const size_t TD = (size_t)TT_C * D_C;
  bf16*  emb   = (bf16*)alloc(TD * 2);
  float* q     = (float*)alloc(TD * 4);
  float* t0    = (float*)alloc(TD * 4);
  float* t1    = (float*)alloc(TD * 4);
  float* al    = (float*)alloc((size_t)TE_C * 8 * 4);
  float* mpart = (float*)alloc((size_t)SPL * TT_C * NH_C * 4);
  float* lpart = (float*)alloc((size_t)SPL * TT_C * NH_C * 4);
  float* ybig  = (float*)alloc((size_t)TT_C * 512 * 4);   // also Opart alias
  size_t base_end = off;

  const size_t KV_FULL = (size_t)B_C * HW_C * 512 * 2;       // 52.43 MB
  const size_t KV_CHNK = (size_t)4 * HW_C * 512 * 2;         // 6.55 MB
  const size_t HM_SZ   = (size_t)(TN_C + TE_C) * HW_C * 2;   // 9.83 MB
  const size_t YB2_SZ  = (size_t)TT_C * 512 * 4;             // 6.29 MB
  const size_t FB_SZ   = (size_t)B_C * HW_C * 256 * 2;       // 26.2 MB
  const size_t MARGIN  = 2u << 20;
  int mode;
  if (ws_size >= base_end + YB2_SZ + KV_FULL + HM_SZ + FB_SZ + MARGIN) mode = 3;
  else if (ws_size >= base_end + KV_FULL + HM_SZ + MARGIN) mode = 2;
  else if (ws_size >= base_end + KV_CHNK + HM_SZ + MARGIN) mode = 1;
  else mode = 0;

  float* ybig2 = (mode == 3) ? (float*)alloc(YB2_SZ) : nullptr;  // contiguous w/ ybig
  bf16* KV = (bf16*)alloc(mode >= 2 ? KV_FULL : KV_CHNK);
  bf16 *nhm = nullptr, *ehm = nullptr;
  if (mode >= 1) {
    nhm = (bf16*)alloc((size_t)TN_C * HW_C * 2);
    ehm = (bf16*)alloc((size_t)TE_C * HW_C * 2);
  }
  bf16* featb = (mode == 3) ? (bf16*)alloc(FB_SZ) : nullptr;
  float* hee   = ybig;
  float* noutp = ybig + (size_t)TT_C * 256;
  float* Opart = ybig;
  (void)in_sizes; (void)n_in; (void)out_size; (void)ybig2;

  embq_kernel<<<TT_C, 256, 0, stream>>>(boxes, edge_local, emb);
  initq_kernel<<<TT_C, 256, 0, stream>>>(nodes0, edges0, q);
  if (mode >= 1) {
    nodehm_kernel<<<TN_C, 256, 0, stream>>>(boxes, nhm);
    edgehm_kernel<<<TE_C, 256, 0, stream>>>(boxes, edge_local, nhm, ehm);
  }
  if (mode == 3)
    featconv_kernel<<<(B_C * HW_C * 256) / (256 * 8), 256, 0, stream>>>(features, featb);

  for (int l = 0; l < L_C; l++) {
    const float* Wq  = attn_in_w + (size_t)l * 768 * 256;
    const float* WKV = Wq + (size_t)256 * 256;
    const float* bq  = attn_in_b + (size_t)l * 768;
    const float* bKV = bq + 256;

    // LN1: q -> t0
    ln_kernel<<<TT_C, 256, 0, stream>>>(q, nullptr, nullptr, nullptr,
                                        ln1_g + l * 256, ln1_b + l * 256,
                                        t0, nullptr, nullptr);
    // Q projection -> t1
    mg<false, true, 1, float>(t0, 256, Wq, 256, bq, t1, 256, TT_C, 256, 256, stream);
    // K/V projection + attention
    if (mode >= 2) {
      if (mode == 3)
        mg<true, true, 1, bf16>(featb, 256, WKV, 256, bKV, KV, 512,
                                B_C * HW_C, 512, 256, stream);
      else
        mg<false, true, 1, bf16>(features, 256, WKV, 256, bKV, KV, 512,
                                 B_C * HW_C, 512, 256, stream);
      fattn_kernel<<<SPL * 256, 192, 0, stream>>>(t1, KV, nhm, ehm,
                                                  Opart, mpart, lpart);
      fmerge_kernel<<<(TT_C * D_C) / 256, 256, 0, stream>>>(Opart, mpart, lpart, t0);
    } else {
      for (int c = 0; c < B_C / 4; c++) {
        mg<false, true, 1, bf16>(features + (size_t)c * 4 * HW_C * 256, 256,
                                 WKV, 256, bKV, KV, 512, 4 * HW_C, 512, 256, stream);
        if (mode == 1)
          attn_kernel<true><<<4 * 192, 256, 0, stream>>>(
              t1, KV, nhm, ehm, boxes, edge_local, c * 4, 4, t0);
        else
          attn_kernel<false><<<4 * 192, 256, 0, stream>>>(
              t1, KV, nhm, ehm, boxes, edge_local, c * 4, 4, t0);
      }
    }
    // output projection -> t1
    mg<false, true, 1, float>(t0, 256, attn_out_w + (size_t)l * 65536, 256,
                              attn_out_b + l * 256, t1, 256, TT_C, 256, 256, stream);
    // LN2 (fused q += ls1*t1): -> q, x2=t0, xe=t1
    ln_kernel<<<TT_C, 256, 0, stream>>>(q, t1, ls1 + l * 256, q,
                                        ln2_g + l * 256, ln2_b + l * 256,
                                        t0, emb, t1);
    // GAT projections (dual) -> hee
    {
      dim3 g(TT_C / 64, 4);
      mgemm_dual_kernel<0><<<g, 256, 0, stream>>>(
          t1, t1 + (size_t)TN_C * 256, TN_C, 256,
          gat_wn + (size_t)l * 65536, gat_we + (size_t)l * 65536, 256,
          nullptr, nullptr, hee, 256, 256);
    }
    gat_fused_kernel<<<B_C, 512, 0, stream>>>(
        hee, edge_local, gat_a_src + l * 256, gat_a_dst + l * 256,
        gat_a_edge + l * 256, al);
    gat_nout_kernel<<<TN_C, 256, 0, stream>>>(hee, edge_local, al, noutp);
    // GAT output projections (dual) -> t1
    {
      dim3 g(TT_C / 64, 4);
      mgemm_dual_kernel<1><<<g, 256, 0, stream>>>(
          noutp, hee + (size_t)TN_C * 256, TN_C, 256,
          gat_wo + (size_t)l * 65536, gat_woe + (size_t)l * 65536, 256,
          gat_bo + l * 256, gat_boe + l * 256, t1, 256, 256);
    }
    // LN3 (fused q = x2 + ls2*t1): -> q, t0
    ln_kernel<<<TT_C, 256, 0, stream>>>(t0, t1, ls2 + l * 256, q,
                                        ln3_g + l * 256, ln3_b + l * 256,
                                        t0, nullptr, nullptr);
    // FFN
    const float* W1 = ffn_w1 + (size_t)l * 262144;
    const float* W2 = ffn_w2 + (size_t)l * 262144;
    if (mode == 3) {
      mg<false, false, 2, float>(t0, 256, W1, 1024, ffn_b1 + l * 1024,
                                 ybig, 1024, TT_C, 1024, 256, stream);
      mg<false, false, 1, float>(ybig, 1024, W2, 256, ffn_b2 + l * 256,
                                 t1, 256, TT_C, 256, 1024, stream);
    } else {
      mg<false, false, 2, float>(t0, 256, W1, 1024, ffn_b1 + l * 1024,
                                 ybig, 512, TT_C, 512, 256, stream);
      mg<false, false, 1, float>(ybig, 512, W2, 256, ffn_b2 + l * 256,
                                 t1, 256, TT_C, 256, 512, stream);
      mg<false, false, 2, float>(t0, 256, W1 + 512, 1024, ffn_b1 + l * 1024 + 512,
                                 ybig, 512, TT_C, 512, 256, stream);
      mg<false, false, 3, float>(ybig, 512, W2 + (size_t)512 * 256, 256,
                                 nullptr, t1, 256, TT_C, 256, 512, stream);
    }
    // q += ls3 * t1 ; store (sanitized)
    axpy_store_kernel<<<TT_C, 256, 0, stream>>>(q, t1, ls3 + l * 256,
                                                out + (size_t)l * TD);
  }
}